// Round 16
// baseline (5282.346 us; speedup 1.0000x reference)
//
#include <hip/hip_runtime.h>
#include <hip/hip_bf16.h>
#include <stdint.h>

#define BB 512
#define LL 77
#define DD 512
#define HH 8
#define NLAYER 12
#define NTOK (BB*LL)        // 39424 = 308*128

typedef __bf16 bf16x8 __attribute__((ext_vector_type(8)));
typedef float f32x4 __attribute__((ext_vector_type(4)));

__device__ inline unsigned short f2bf(float f) {
  unsigned u = __float_as_uint(f);
  u += 0x7fffu + ((u >> 16) & 1u);
  return (unsigned short)(u >> 16);
}
__device__ inline float bf2f(unsigned short s) {
  return __uint_as_float(((unsigned)s) << 16);
}
__device__ inline unsigned pack2(float a, float b) {
  return (unsigned)f2bf(a) | ((unsigned)f2bf(b) << 16);
}
__device__ inline void gload16(const void* g, void* l) {
  __builtin_amdgcn_global_load_lds(
      (const __attribute__((address_space(1))) void*)g,
      (__attribute__((address_space(3))) void*)l, 16, 0, 0);
}

// bijective XCD-aware remap (m204 formula)
__device__ inline void xcd_remap(int& bx, int& by) {
  const int gx = gridDim.x, gy = gridDim.y;
  const int nwg = gx * gy;
  int flat = blockIdx.y * gx + blockIdx.x;
  const int q = nwg >> 3, r = nwg & 7;
  const int xcd = flat & 7, lo = flat >> 3;
  int nf = (xcd < r) ? (xcd * (q + 1) + lo) : (r * (q + 1) + (xcd - r) * q + lo);
  bx = nf % gx; by = nf / gx;
}

__global__ void diag_kernel(float* out, float v) { out[0] = v; }

// ---------------- embed: x = bf16(prompts + pos_emb) ----------------
__global__ void embed_kernel(const float4* __restrict__ p,
                             const float4* __restrict__ pe,
                             uint2* __restrict__ x) {
  int r = blockIdx.x;
  int t = threadIdx.x;           // 0..127, 4 elems each
  int l = r % LL;
  float4 a = p[(size_t)r*128 + t];
  float4 b = pe[(size_t)l*128 + t];
  uint2 o; o.x = pack2(a.x+b.x, a.y+b.y); o.y = pack2(a.z+b.z, a.w+b.w);
  x[(size_t)r*128 + t] = o;
}

// ---------------- lengths = argmax(tokens)+1 ----------------
__global__ void lengths_kernel(const int* __restrict__ tok, int* __restrict__ len) {
  int b = blockIdx.x; int lane = threadIdx.x;
  int bv = -2147483647, bi = 0;
  for (int j = lane; j < LL; j += 64) {
    int v = tok[b*LL + j];
    if (v > bv) { bv = v; bi = j; }
  }
  for (int off = 32; off; off >>= 1) {
    int ov = __shfl_down(bv, off);
    int oi = __shfl_down(bi, off);
    if (ov > bv || (ov == bv && oi < bi)) { bv = ov; bi = oi; }
  }
  if (lane == 0) len[b] = bi + 1;
}

// mask value per reference where-chain (P=1, C=10 -> [1,11))
__device__ inline float maskv(int i, int j, int Lb) {
  const float NEG = -1e30f;
  float m = (j > i) ? NEG : 0.f;
  bool ctx = (i >= 1 && i < 11);
  if (ctx && j < Lb) m = 0.f;
  if (i >= 11 && i < Lb && j >= 1 && j < 11) m = NEG;
  if (ctx && j >= 1 && j < 11) m = NEG;
  if (j >= Lb) m = NEG;
  bool eot = (i == Lb - 1);
  if (eot && j < 11) m = 0.f;
  if (eot && j >= 11 && j < Lb) m = 0.1f;
  return m;
}

// ---------------- f32 -> bf16 convert ----------------
__global__ void cvt_kernel(const float4* __restrict__ s, uint2* __restrict__ d, int n4) {
  for (int i = blockIdx.x*blockDim.x + threadIdx.x; i < n4; i += gridDim.x*blockDim.x) {
    float4 v = s[i];
    uint2 o; o.x = pack2(v.x, v.y); o.y = pack2(v.z, v.w);
    d[i] = o;
  }
}

// ---------------- transpose text_projection (D,PROJ) -> W[PROJ][D] bf16 ----------------
__global__ void tpT_kernel(const float* __restrict__ tp, unsigned short* __restrict__ W) {
  int p = blockIdx.x;
  for (int d = threadIdx.x; d < DD; d += 256)
    W[(size_t)p*DD + d] = f2bf(tp[(size_t)d*DD + p]);
}

// ---------------- LayerNorm row of 512 (bf16 in) -> bf16 out (one wave per row) ----------------
__global__ __launch_bounds__(256) void ln_kernel(const unsigned short* __restrict__ X,
    const float* __restrict__ w, const float* __restrict__ bia,
    unsigned short* __restrict__ Oh) {
  int row = blockIdx.x*4 + (threadIdx.x >> 6);
  int lane = threadIdx.x & 63;
  uint4 pk = *(const uint4*)(X + (size_t)row*DD + lane*8);
  float v[8];
  v[0]=bf2f(pk.x&0xffff); v[1]=bf2f(pk.x>>16);
  v[2]=bf2f(pk.y&0xffff); v[3]=bf2f(pk.y>>16);
  v[4]=bf2f(pk.z&0xffff); v[5]=bf2f(pk.z>>16);
  v[6]=bf2f(pk.w&0xffff); v[7]=bf2f(pk.w>>16);
  float s = 0.f, q = 0.f;
  #pragma unroll
  for (int i = 0; i < 8; ++i) { s += v[i]; q += v[i]*v[i]; }
  for (int off = 1; off < 64; off <<= 1) { s += __shfl_xor(s, off); q += __shfl_xor(q, off); }
  float mu = s * (1.f/DD);
  float var = q * (1.f/DD) - mu*mu;
  float rs = rsqrtf(var + 1e-5f);
  const float* wp = w + lane*8; const float* bp = bia + lane*8;
  float4 w0 = *(const float4*)wp;  float4 w1 = *(const float4*)(wp+4);
  float4 b0 = *(const float4*)bp;  float4 b1 = *(const float4*)(bp+4);
  float o0 = (v[0]-mu)*rs*w0.x + b0.x;
  float o1 = (v[1]-mu)*rs*w0.y + b0.y;
  float o2 = (v[2]-mu)*rs*w0.z + b0.z;
  float o3 = (v[3]-mu)*rs*w0.w + b0.w;
  float o4 = (v[4]-mu)*rs*w1.x + b1.x;
  float o5 = (v[5]-mu)*rs*w1.y + b1.y;
  float o6 = (v[6]-mu)*rs*w1.z + b1.z;
  float o7 = (v[7]-mu)*rs*w1.w + b1.w;
  uint4 ok; ok.x = pack2(o0,o1); ok.y = pack2(o2,o3); ok.z = pack2(o4,o5); ok.w = pack2(o6,o7);
  *(uint4*)(Oh + (size_t)row*DD + lane*8) = ok;
}

// ---------------- final LN at eot row per batch (bf16 in) ----------------
__global__ void eot_ln_kernel(const unsigned short* __restrict__ X, const int* __restrict__ len,
    const float* __restrict__ w, const float* __restrict__ bia,
    unsigned short* __restrict__ Xe) {
  int b = blockIdx.x; int lane = threadIdx.x;
  int row = len[b] - 1;
  uint4 pk = *(const uint4*)(X + ((size_t)b*LL + row)*DD + lane*8);
  float v[8];
  v[0]=bf2f(pk.x&0xffff); v[1]=bf2f(pk.x>>16);
  v[2]=bf2f(pk.y&0xffff); v[3]=bf2f(pk.y>>16);
  v[4]=bf2f(pk.z&0xffff); v[5]=bf2f(pk.z>>16);
  v[6]=bf2f(pk.w&0xffff); v[7]=bf2f(pk.w>>16);
  float s = 0.f, q = 0.f;
  #pragma unroll
  for (int i = 0; i < 8; ++i) { s += v[i]; q += v[i]*v[i]; }
  for (int off = 1; off < 64; off <<= 1) { s += __shfl_xor(s, off); q += __shfl_xor(q, off); }
  float mu = s * (1.f/DD);
  float var = q * (1.f/DD) - mu*mu;
  float rs = rsqrtf(var + 1e-5f);
  const float* wp = w + lane*8; const float* bp = bia + lane*8;
  float4 w0 = *(const float4*)wp;  float4 w1 = *(const float4*)(wp+4);
  float4 b0 = *(const float4*)bp;  float4 b1 = *(const float4*)(bp+4);
  float o0 = (v[0]-mu)*rs*w0.x + b0.x;
  float o1 = (v[1]-mu)*rs*w0.y + b0.y;
  float o2 = (v[2]-mu)*rs*w0.z + b0.z;
  float o3 = (v[3]-mu)*rs*w0.w + b0.w;
  float o4 = (v[4]-mu)*rs*w1.x + b1.x;
  float o5 = (v[5]-mu)*rs*w1.y + b1.y;
  float o6 = (v[6]-mu)*rs*w1.z + b1.z;
  float o7 = (v[7]-mu)*rs*w1.w + b1.w;
  uint4 ok; ok.x = pack2(o0,o1); ok.y = pack2(o2,o3); ok.z = pack2(o4,o5); ok.w = pack2(o6,o7);
  *(uint4*)(Xe + (size_t)b*DD + lane*8) = ok;
}

// ---------------- GEMM: C[M,N] = A[M,K] @ W[N,K]^T ----------------
// R16: 2-deep counted pipeline, correct by construction.
//  - dbuf 64KB LDS (2 blocks/CU, launch_bounds(256,2) -> 256-reg budget, no spill)
//  - per tile t: pull ALL 16 frags to regs -> lgkmcnt(0)+s_barrier (read-done)
//    -> stage tile t+2 into freed buffer (WAR-safe) -> 32 MFMA from regs
//    -> counted vmcnt(8) (waits only tile t+1, issued a full phase ago; tail: vmcnt(0))
//    -> s_barrier. Never drains own prefetch.
// EPI 0: bias->bf16. EPI 1: bias+gelu->bf16. EPI 2: residual RMW (LDS slab, uint4). EPI 3: f32.
template<int EPI>
__global__ __launch_bounds__(256, 2) void gemm_bt(
    const unsigned short* __restrict__ A,
    const unsigned short* __restrict__ W,
    const float* __restrict__ bias,
    unsigned short* __restrict__ Ob,
    float* __restrict__ Of,
    int N, int K)
{
  __shared__ __align__(16) char smem[65536];      // As[2] 32KB | Bs[2] 32KB
  unsigned short* As0 = (unsigned short*)smem;
  unsigned short* Bs0 = (unsigned short*)(smem + 32768);
  int bx, by;
  xcd_remap(bx, by);
  const int tid = threadIdx.x;
  const int lane = tid & 63;
  const int wid = tid >> 6;
  const int wr = wid >> 1, wc = wid & 1;
  const int m0 = by * 128, n0 = bx * 128;

  f32x4 acc[4][4] = {};

  const int r0 = tid >> 3;                       // 0..31 (row within 32-row group)
  const int cb = (((tid & 7) ^ (r0 & 7)) * 8);   // swizzled source 16B-unit
  const unsigned voff = (unsigned)(r0 * K + cb); // per-thread, loop-invariant

  const int c = lane & 15, gq = lane >> 4;
  const int aBase = (wr*64 + c)*64;
  const int bBase = (wc*64 + c)*64;
  const int sw0 = ((0*4 + gq) ^ (c & 7)) * 8;
  const int sw1 = ((1*4 + gq) ^ (c & 7)) * 8;

  auto stage = [&](int buf, int kt) {
    unsigned short* Ad = As0 + buf*8192;
    unsigned short* Bd = Bs0 + buf*8192;
    const unsigned short* pA = A + (size_t)m0 * K + kt*64;   // wave-uniform
    const unsigned short* pW = W + (size_t)n0 * K + kt*64;
    #pragma unroll
    for (int g = 0; g < 4; ++g) {
      gload16(pA + (size_t)g*32*K + voff, Ad + g*2048 + tid*8);
      gload16(pW + (size_t)g*32*K + voff, Bd + g*2048 + tid*8);
    }
  };

  const int nt = K >> 6;       // >= 8 for all our K
  stage(0, 0);
  if (nt > 1) {
    stage(1, 1);
    asm volatile("s_waitcnt vmcnt(8)" ::: "memory");   // tile 0 landed
  } else {
    asm volatile("s_waitcnt vmcnt(0)" ::: "memory");
  }
  __builtin_amdgcn_sched_barrier(0);
  __builtin_amdgcn_s_barrier();

  int cur = 0;
  for (int t = 0; t < nt; ++t) {
    const unsigned short* Ab = As0 + cur*8192;
    const unsigned short* Bb = Bs0 + cur*8192;
    bf16x8 af[2][4], bfr[2][4];
    #pragma unroll
    for (int kk = 0; kk < 2; ++kk) {
      const int sw = kk ? sw1 : sw0;
      #pragma unroll
      for (int mi = 0; mi < 4; ++mi)
        af[kk][mi] = *(const bf16x8*)(Ab + aBase + sw + mi*1024);
      #pragma unroll
      for (int ni = 0; ni < 4; ++ni)
        bfr[kk][ni] = *(const bf16x8*)(Bb + bBase + sw + ni*1024);
    }
    asm volatile("s_waitcnt lgkmcnt(0)" ::: "memory");  // this wave's reads -> regs
    __builtin_amdgcn_sched_barrier(0);
    __builtin_amdgcn_s_barrier();                       // ALL waves done reading buf[cur]
    if (t + 2 < nt) stage(cur, t + 2);                  // WAR-safe overwrite
    #pragma unroll
    for (int kk = 0; kk < 2; ++kk)
      #pragma unroll
      for (int mi = 0; mi < 4; ++mi)
        #pragma unroll
        for (int ni = 0; ni < 4; ++ni)
          acc[mi][ni] = __builtin_amdgcn_mfma_f32_16x16x32_bf16(af[kk][mi], bfr[kk][ni], acc[mi][ni], 0, 0, 0);
    if (t + 1 < nt) {
      if (t + 2 < nt)
        asm volatile("s_waitcnt vmcnt(8)" ::: "memory"); // tile t+1 landed (t+2's 8 may fly)
      else
        asm volatile("s_waitcnt vmcnt(0)" ::: "memory"); // tail: no newer loads to shield
      __builtin_amdgcn_sched_barrier(0);
      __builtin_amdgcn_s_barrier();                      // tile t+1 visible to all waves
    }
    cur ^= 1;
  }
  __syncthreads();   // full drain once: epilogue slab aliases As0

  if constexpr (EPI == 2) {
    // per-wave private f32 slab [16][68] (pad 68 -> 2-way-free writes), 4352 B/wave
    float* slab = (float*)smem + wid*1088;
    const int rr = lane >> 3;            // 0..7
    const int c8 = (lane & 7) * 8;       // 0..56
    const int gcol = n0 + wc*64 + c8;
    float4 bq0 = *(const float4*)(bias + gcol);
    float4 bq1 = *(const float4*)(bias + gcol + 4);
    float badd[8] = {bq0.x,bq0.y,bq0.z,bq0.w,bq1.x,bq1.y,bq1.z,bq1.w};
    #pragma unroll
    for (int mi = 0; mi < 4; ++mi) {
      #pragma unroll
      for (int ni = 0; ni < 4; ++ni)
        #pragma unroll
        for (int j = 0; j < 4; ++j)
          slab[(gq*4 + j)*68 + ni*16 + c] = acc[mi][ni][j];
      // in-wave LDS ordering (lgkmcnt) makes reads see the writes above
      #pragma unroll
      for (int q = 0; q < 2; ++q) {
        int r = q*8 + rr;
        int grow = m0 + wr*64 + mi*16 + r;
        size_t ix = (size_t)grow * N + gcol;
        uint4 old = *(const uint4*)(Ob + ix);
        float vv[8];
        #pragma unroll
        for (int i = 0; i < 8; ++i) vv[i] = slab[r*68 + c8 + i] + badd[i];
        unsigned ow[4] = {old.x, old.y, old.z, old.w};
        uint4 res; unsigned* rp = (unsigned*)&res;
        #pragma unroll
        for (int h = 0; h < 4; ++h) {
          float a0 = vv[h*2]   + bf2f((unsigned short)(ow[h] & 0xffff));
          float a1 = vv[h*2+1] + bf2f((unsigned short)(ow[h] >> 16));
          rp[h] = pack2(a0, a1);
        }
        *(uint4*)(Ob + ix) = res;      // 16B/lane coalesced full-line RMW
      }
    }
  } else {
    const int rbase = m0 + wr*64 + gq*4;
    const int cbase = n0 + wc*64 + c;
    #pragma unroll
    for (int mi = 0; mi < 4; ++mi) {
      #pragma unroll
      for (int ni = 0; ni < 4; ++ni) {
        int col = cbase + ni*16;
        float bv = 0.f;
        if constexpr (EPI != 3) bv = bias[col];
        #pragma unroll
        for (int j = 0; j < 4; ++j) {
          int row = rbase + mi*16 + j;
          float v = acc[mi][ni][j] + bv;
          size_t ix = (size_t)row*N + col;
          if constexpr (EPI == 0) {
            Ob[ix] = f2bf(v);
          } else if constexpr (EPI == 1) {
            float sg = 1.f/(1.f + __expf(-1.702f*v));
            Ob[ix] = f2bf(v*sg);
          } else {
            Of[ix] = v;
          }
        }
      }
    }
  }
}

// ---------------- MFMA attention: one block per (b_local, h), 5 waves ----------------
#define QS 72    // q/k LDS row stride (elems); +8 pad -> conflict-free frag reads
#define VS 104   // vt/p LDS row stride (elems)

__global__ __launch_bounds__(320) void attn_mfma(
    const unsigned short* __restrict__ qkv,   // [chT][1536] chunk-local bf16
    const int* __restrict__ len,              // pre-offset to chunk's batches
    unsigned short* __restrict__ O)           // [chT][512] chunk-local bf16
{
  __shared__ __align__(16) unsigned short q_s[80*QS];
  __shared__ __align__(16) unsigned short k_s[80*QS];
  __shared__ __align__(16) unsigned short vt_s[64*VS];
  __shared__ __align__(16) unsigned short p_s[80*VS];
  const int bh = blockIdx.x;
  const int b = bh >> 3, h = bh & 7;
  const int tid = threadIdx.x, lane = tid & 63, g = lane >> 4, c = lane & 15;
  const int Lb = len[b];
  const size_t base = (size_t)b*LL*1536 + h*64;

  for (int idx = tid; idx < 640; idx += 320) {    // 80 rows x 8 groups
    int l = idx >> 3, d8 = (idx & 7) * 8;
    uint4 qv = {0,0,0,0}, kv = {0,0,0,0};
    if (l < LL) {
      const unsigned short* gp = qkv + base + (size_t)l*1536 + d8;
      qv = *(const uint4*)gp;
      kv = *(const uint4*)(gp + 512);
    }
    *(uint4*)(q_s + l*QS + d8) = qv;
    *(uint4*)(k_s + l*QS + d8) = kv;
  }
  for (int idx = tid; idx < 64*64; idx += 320) {
    int d = idx >> 6, l = idx & 63;
    vt_s[d*VS + l] = qkv[base + (size_t)l*1536 + 1024 + d];
  }
  for (int idx = tid; idx < 64*32; idx += 320) {
    int d = idx >> 5, l = 64 + (idx & 31);
    vt_s[d*VS + l] = (l < LL) ? qkv[base + (size_t)l*1536 + 1024 + d] : (unsigned short)0;
  }
  for (int idx = tid; idx < 80*16; idx += 320) {
    int r = idx >> 4, cc = 80 + (idx & 15);
    p_s[r*VS + cc] = 0;
  }
  __syncthreads();

  for (int s = (tid >> 6); s < 5; s += 5) {       // one strip per wave
    const int m0 = s*16;
    bf16x8 aq0 = *(const bf16x8*)(q_s + (m0 + c)*QS + g*8);
    bf16x8 aq1 = *(const bf16x8*)(q_s + (m0 + c)*QS + 32 + g*8);
    f32x4 sc[5];
    #pragma unroll
    for (int nt = 0; nt < 5; ++nt) {
      bf16x8 bk0 = *(const bf16x8*)(k_s + (nt*16 + c)*QS + g*8);
      bf16x8 bk1 = *(const bf16x8*)(k_s + (nt*16 + c)*QS + 32 + g*8);
      f32x4 z = {};
      z = __builtin_amdgcn_mfma_f32_16x16x32_bf16(aq0, bk0, z, 0, 0, 0);
      sc[nt] = __builtin_amdgcn_mfma_f32_16x16x32_bf16(aq1, bk1, z, 0, 0, 0);
    }
    #pragma unroll
    for (int j = 0; j < 4; ++j) {
      int r = m0 + g*4 + j;
      float sv[5];
      float mx = -3.4e38f;
      #pragma unroll
      for (int nt = 0; nt < 5; ++nt) {
        sv[nt] = sc[nt][j]*0.125f + maskv(r, nt*16 + c, Lb);
        mx = fmaxf(mx, sv[nt]);
      }
      mx = fmaxf(mx, __shfl_xor(mx, 1));
      mx = fmaxf(mx, __shfl_xor(mx, 2));
      mx = fmaxf(mx, __shfl_xor(mx, 4));
      mx = fmaxf(mx, __shfl_xor(mx, 8));
      float sum = 0.f;
      #pragma unroll
      for (int nt = 0; nt < 5; ++nt) { sv[nt] = __expf(sv[nt] - mx); sum += sv[nt]; }
      sum += __shfl_xor(sum, 1); sum += __shfl_xor(sum, 2);
      sum += __shfl_xor(sum, 4); sum += __shfl_xor(sum, 8);
      float inv = 1.f / sum;
      #pragma unroll
      for (int nt = 0; nt < 5; ++nt)
        p_s[r*VS + nt*16 + c] = f2bf(sv[nt] * inv);
    }
    f32x4 oa[4] = {};
    #pragma unroll
    for (int kk = 0; kk < 3; ++kk) {
      bf16x8 ap = *(const bf16x8*)(p_s + (m0 + c)*VS + kk*32 + g*8);
      #pragma unroll
      for (int nt = 0; nt < 4; ++nt) {
        bf16x8 bv = *(const bf16x8*)(vt_s + (nt*16 + c)*VS + kk*32 + g*8);
        oa[nt] = __builtin_amdgcn_mfma_f32_16x16x32_bf16(ap, bv, oa[nt], 0, 0, 0);
      }
    }
    #pragma unroll
    for (int nt = 0; nt < 4; ++nt) {
      #pragma unroll
      for (int j = 0; j < 4; ++j) {
        int r = m0 + g*4 + j;
        if (r < LL)
          O[((size_t)b*LL + r)*512 + h*64 + nt*16 + c] = f2bf(oa[nt][j]);
      }
    }
  }
}

extern "C" void kernel_launch(void* const* d_in, const int* in_sizes, int n_in,
                              void* d_out, int out_size, void* d_ws, size_t ws_size,
                              hipStream_t stream) {
  const float* prompts = (const float*)d_in[0];
  const float* pos_emb = (const float*)d_in[1];
  const int*   tokens  = (const int*)d_in[2];
  const float* ln1w    = (const float*)d_in[3];
  const float* ln1b    = (const float*)d_in[4];
  const float* inw     = (const float*)d_in[5];
  const float* inb     = (const float*)d_in[6];
  const float* opw     = (const float*)d_in[7];
  const float* opb     = (const float*)d_in[8];
  const float* ln2w    = (const float*)d_in[9];
  const float* ln2b    = (const float*)d_in[10];
  const float* fcw     = (const float*)d_in[11];
  const float* fcb     = (const float*)d_in[12];
  const float* cpw     = (const float*)d_in[13];
  const float* cpb     = (const float*)d_in[14];
  const float* lnfw    = (const float*)d_in[15];
  const float* lnfb    = (const float*)d_in[16];
  const float* tp      = (const float*)d_in[17];
  float* out = (float*)d_out;

  char* basep = (char*)d_ws;
  size_t off = 0;
  auto carve = [&](size_t bytes) {
    char* p = basep + off;
    off += (bytes + 255) & ~(size_t)255;
    return (void*)p;
  };
  unsigned short* x   = (unsigned short*)carve((size_t)NTOK*DD*2);   // 40.4 MB (bf16 residual)
  unsigned short* hb  = (unsigned short*)carve((size_t)NTOK*DD*2);   // 40.4 MB
  unsigned short* w_tp = (unsigned short*)carve((size_t)512*512*2);
  unsigned short* xe   = (unsigned short*)carve((size_t)BB*DD*2);
  int* len             = (int*)carve((size_t)BB*4);

  // ---- tier selection: PREFER LARGE GRIDS (nch=1) over pre-converted weights ----
  const size_t per_layer_w = (size_t)(1536*512 + 512*512 + 2048*512 + 512*2048);
  size_t rem = (ws_size > off) ? (ws_size - off) : 0;
  auto bigb = [&](int n){ return ((size_t)NTOK/n)*2048*2 + 1024; };
  const size_t wfull = per_layer_w * NLAYER * 2 + 2048;
  const size_t wrot  = per_layer_w * 2 + 2048;
  int nch; bool fullw;
  if      (rem >= bigb(1) + wfull) { nch = 1; fullw = true; }
  else if (rem >= bigb(1) + wrot)  { nch = 1; fullw = false; }
  else if (rem >= bigb(2) + wfull) { nch = 2; fullw = true; }
  else if (rem >= bigb(2) + wrot)  { nch = 2; fullw = false; }
  else if (rem >= bigb(4) + wrot)  { nch = 4; fullw = false; }
  else {
    diag_kernel<<<1, 1, 0, stream>>>(out, 1000.0f + (float)(ws_size >> 20));
    return;
  }
  const int chT = NTOK / nch;   // 39424 / 19712 / 9856 — all divisible by 128
  const int chB = BB / nch;

  unsigned short* big = (unsigned short*)carve((size_t)chT*2048*2);
  unsigned short *w_in, *w_op, *w_fc, *w_cp;
  size_t stride_in = (size_t)1536*512, stride_op = (size_t)512*512;
  size_t stride_fc = (size_t)2048*512, stride_cp = (size_t)512*2048;
  if (fullw) {
    w_in = (unsigned short*)carve(NLAYER*stride_in*2);
    w_op = (unsigned short*)carve(NLAYER*stride_op*2);
    w_fc = (unsigned short*)carve(NLAYER*stride_fc*2);
    w_cp = (unsigned short*)carve(NLAYER*stride_cp*2);
  } else {
    w_in = (unsigned short*)carve(stride_in*2);
    w_op = (unsigned short*)carve(stride_op*2);
    w_fc = (unsigned short*)carve(stride_fc*2);
    w_cp = (unsigned short*)carve(stride_cp*2);
    stride_in = stride_op = stride_fc = stride_cp = 0;
  }

  embed_kernel<<<NTOK, 128, 0, stream>>>((const float4*)prompts, (const float4*)pos_emb, (uint2*)x);
  lengths_kernel<<<BB, 64, 0, stream>>>(tokens, len);
  tpT_kernel<<<512, 256, 0, stream>>>(tp, w_tp);

  if (fullw) {
    cvt_kernel<<<4096, 256, 0, stream>>>((const float4*)inw, (uint2*)w_in, NLAYER*1536*512/4);
    cvt_kernel<<<4096, 256, 0, stream>>>((const float4*)opw, (uint2*)w_op, NLAYER*512*512/4);
    cvt_kernel<<<4096, 256, 0, stream>>>((const float4*)fcw, (uint2*)w_fc, NLAYER*2048*512/4);
    cvt_kernel<<<4096, 256, 0, stream>>>((const float4*)cpw, (uint2*)w_cp, NLAYER*512*2048/4);
  }

  for (int l = 0; l < NLAYER; ++l) {
    if (!fullw) {
      cvt_kernel<<<512, 256, 0, stream>>>((const float4*)(inw + (size_t)l*1536*512), (uint2*)w_in, 1536*512/4);
      cvt_kernel<<<512, 256, 0, stream>>>((const float4*)(opw + (size_t)l*512*512), (uint2*)w_op, 512*512/4);
      cvt_kernel<<<512, 256, 0, stream>>>((const float4*)(fcw + (size_t)l*2048*512), (uint2*)w_fc, 2048*512/4);
      cvt_kernel<<<512, 256, 0, stream>>>((const float4*)(cpw + (size_t)l*512*2048), (uint2*)w_cp, 512*2048/4);
    }
    const unsigned short* lw_in = w_in + (size_t)l*stride_in;
    const unsigned short* lw_op = w_op + (size_t)l*stride_op;
    const unsigned short* lw_fc = w_fc + (size_t)l*stride_fc;
    const unsigned short* lw_cp = w_cp + (size_t)l*stride_cp;

    ln_kernel<<<NTOK/4, 256, 0, stream>>>(x, ln1w + l*DD, ln1b + l*DD, hb);
    for (int c = 0; c < nch; ++c) {
      gemm_bt<0><<<dim3(1536/128, chT/128), 256, 0, stream>>>(
          hb + (size_t)c*chT*DD, lw_in, inb + l*1536, big, nullptr, 1536, 512);
      attn_mfma<<<chB*HH, 320, 0, stream>>>(big, len + c*chB, hb + (size_t)c*chT*DD);
    }
    gemm_bt<2><<<dim3(512/128, NTOK/128), 256, 0, stream>>>(
        hb, lw_op, opb + l*DD, x, nullptr, 512, 512);

    ln_kernel<<<NTOK/4, 256, 0, stream>>>(x, ln2w + l*DD, ln2b + l*DD, hb);
    for (int c = 0; c < nch; ++c) {
      gemm_bt<1><<<dim3(2048/128, chT/128), 256, 0, stream>>>(
          hb + (size_t)c*chT*DD, lw_fc, fcb + l*2048, big, nullptr, 2048, 512);
      gemm_bt<2><<<dim3(512/128, chT/128), 256, 0, stream>>>(
          big, lw_cp, cpb + l*DD, x + (size_t)c*chT*DD, nullptr, 512, 2048);
    }
  }

  eot_ln_kernel<<<BB, 64, 0, stream>>>(x, len, lnfw, lnfb, xe);
  gemm_bt<3><<<dim3(512/128, 512/128), 256, 0, stream>>>(
      xe, w_tp, nullptr, nullptr, out, 512, 512);
}

// Round 17
// 4690.620 us; speedup vs baseline: 1.1262x; 1.1262x over previous
//
#include <hip/hip_runtime.h>
#include <hip/hip_bf16.h>
#include <stdint.h>

#define BB 512
#define LL 77
#define DD 512
#define HH 8
#define NLAYER 12
#define NTOK (BB*LL)        // 39424 = 308*128

typedef __bf16 bf16x8 __attribute__((ext_vector_type(8)));
typedef float f32x4 __attribute__((ext_vector_type(4)));

__device__ inline unsigned short f2bf(float f) {
  unsigned u = __float_as_uint(f);
  u += 0x7fffu + ((u >> 16) & 1u);
  return (unsigned short)(u >> 16);
}
__device__ inline float bf2f(unsigned short s) {
  return __uint_as_float(((unsigned)s) << 16);
}
__device__ inline unsigned pack2(float a, float b) {
  return (unsigned)f2bf(a) | ((unsigned)f2bf(b) << 16);
}
__device__ inline void gload16(const void* g, void* l) {
  __builtin_amdgcn_global_load_lds(
      (const __attribute__((address_space(1))) void*)g,
      (__attribute__((address_space(3))) void*)l, 16, 0, 0);
}

// bijective XCD-aware remap (m204 formula)
__device__ inline void xcd_remap(int& bx, int& by) {
  const int gx = gridDim.x, gy = gridDim.y;
  const int nwg = gx * gy;
  int flat = blockIdx.y * gx + blockIdx.x;
  const int q = nwg >> 3, r = nwg & 7;
  const int xcd = flat & 7, lo = flat >> 3;
  int nf = (xcd < r) ? (xcd * (q + 1) + lo) : (r * (q + 1) + (xcd - r) * q + lo);
  bx = nf % gx; by = nf / gx;
}

__global__ void diag_kernel(float* out, float v) { out[0] = v; }

// ---------------- lengths = argmax(tokens)+1 ----------------
__global__ void lengths_kernel(const int* __restrict__ tok, int* __restrict__ len) {
  int b = blockIdx.x; int lane = threadIdx.x;
  int bv = -2147483647, bi = 0;
  for (int j = lane; j < LL; j += 64) {
    int v = tok[b*LL + j];
    if (v > bv) { bv = v; bi = j; }
  }
  for (int off = 32; off; off >>= 1) {
    int ov = __shfl_down(bv, off);
    int oi = __shfl_down(bi, off);
    if (ov > bv || (ov == bv && oi < bi)) { bv = ov; bi = oi; }
  }
  if (lane == 0) len[b] = bi + 1;
}

// ---------------- exclusive prefix over lengths + total Mc ----------------
__global__ void scan_kernel(const int* __restrict__ len, int* __restrict__ pref,
                            int* __restrict__ mc) {
  __shared__ int sm[512];
  int t = threadIdx.x;
  sm[t] = len[t];
  __syncthreads();
  for (int off = 1; off < 512; off <<= 1) {
    int v = (t >= off) ? sm[t - off] : 0;
    __syncthreads();
    sm[t] += v;
    __syncthreads();
  }
  pref[t + 1] = sm[t];
  if (t == 0) pref[0] = 0;
  if (t == 511) *mc = sm[511];
}

// ---------------- embed (compact gather): x[pref[b]+l] = bf16(prompts+pe) ----------------
__global__ void embed_kernel(const float4* __restrict__ p,
                             const float4* __restrict__ pe,
                             const int* __restrict__ len,
                             const int* __restrict__ pref,
                             uint2* __restrict__ x) {
  int r = blockIdx.x;
  int t = threadIdx.x;           // 0..127, 4 elems each
  int b = r / LL, l = r - b*LL;
  if (l >= len[b]) return;       // dead row
  float4 a = p[(size_t)r*128 + t];
  float4 bb = pe[(size_t)l*128 + t];
  uint2 o; o.x = pack2(a.x+bb.x, a.y+bb.y); o.y = pack2(a.z+bb.z, a.w+bb.w);
  x[(size_t)(pref[b] + l)*128 + t] = o;
}

// mask value per reference where-chain (P=1, C=10 -> [1,11))
__device__ inline float maskv(int i, int j, int Lb) {
  const float NEG = -1e30f;
  float m = (j > i) ? NEG : 0.f;
  bool ctx = (i >= 1 && i < 11);
  if (ctx && j < Lb) m = 0.f;
  if (i >= 11 && i < Lb && j >= 1 && j < 11) m = NEG;
  if (ctx && j >= 1 && j < 11) m = NEG;
  if (j >= Lb) m = NEG;
  bool eot = (i == Lb - 1);
  if (eot && j < 11) m = 0.f;
  if (eot && j >= 11 && j < Lb) m = 0.1f;
  return m;
}

// ---------------- f32 -> bf16 convert ----------------
__global__ void cvt_kernel(const float4* __restrict__ s, uint2* __restrict__ d, int n4) {
  for (int i = blockIdx.x*blockDim.x + threadIdx.x; i < n4; i += gridDim.x*blockDim.x) {
    float4 v = s[i];
    uint2 o; o.x = pack2(v.x, v.y); o.y = pack2(v.z, v.w);
    d[i] = o;
  }
}

// ---------------- transpose text_projection (D,PROJ) -> W[PROJ][D] bf16 ----------------
__global__ void tpT_kernel(const float* __restrict__ tp, unsigned short* __restrict__ W) {
  int p = blockIdx.x;
  for (int d = threadIdx.x; d < DD; d += 256)
    W[(size_t)p*DD + d] = f2bf(tp[(size_t)d*DD + p]);
}

// ---------------- LayerNorm row of 512 (bf16 in) -> bf16 out; compact rows < Mc --------
__global__ __launch_bounds__(256) void ln_kernel(const unsigned short* __restrict__ X,
    const float* __restrict__ w, const float* __restrict__ bia,
    unsigned short* __restrict__ Oh, const int* __restrict__ mcp) {
  int row = blockIdx.x*4 + (threadIdx.x >> 6);
  if (row >= *mcp) return;
  int lane = threadIdx.x & 63;
  uint4 pk = *(const uint4*)(X + (size_t)row*DD + lane*8);
  float v[8];
  v[0]=bf2f(pk.x&0xffff); v[1]=bf2f(pk.x>>16);
  v[2]=bf2f(pk.y&0xffff); v[3]=bf2f(pk.y>>16);
  v[4]=bf2f(pk.z&0xffff); v[5]=bf2f(pk.z>>16);
  v[6]=bf2f(pk.w&0xffff); v[7]=bf2f(pk.w>>16);
  float s = 0.f, q = 0.f;
  #pragma unroll
  for (int i = 0; i < 8; ++i) { s += v[i]; q += v[i]*v[i]; }
  for (int off = 1; off < 64; off <<= 1) { s += __shfl_xor(s, off); q += __shfl_xor(q, off); }
  float mu = s * (1.f/DD);
  float var = q * (1.f/DD) - mu*mu;
  float rs = rsqrtf(var + 1e-5f);
  const float* wp = w + lane*8; const float* bp = bia + lane*8;
  float4 w0 = *(const float4*)wp;  float4 w1 = *(const float4*)(wp+4);
  float4 b0 = *(const float4*)bp;  float4 b1 = *(const float4*)(bp+4);
  float o0 = (v[0]-mu)*rs*w0.x + b0.x;
  float o1 = (v[1]-mu)*rs*w0.y + b0.y;
  float o2 = (v[2]-mu)*rs*w0.z + b0.z;
  float o3 = (v[3]-mu)*rs*w0.w + b0.w;
  float o4 = (v[4]-mu)*rs*w1.x + b1.x;
  float o5 = (v[5]-mu)*rs*w1.y + b1.y;
  float o6 = (v[6]-mu)*rs*w1.z + b1.z;
  float o7 = (v[7]-mu)*rs*w1.w + b1.w;
  uint4 ok; ok.x = pack2(o0,o1); ok.y = pack2(o2,o3); ok.z = pack2(o4,o5); ok.w = pack2(o6,o7);
  *(uint4*)(Oh + (size_t)row*DD + lane*8) = ok;
}

// ---------------- final LN at eot row per batch (compact) ----------------
__global__ void eot_ln_kernel(const unsigned short* __restrict__ X, const int* __restrict__ len,
    const int* __restrict__ pref,
    const float* __restrict__ w, const float* __restrict__ bia,
    unsigned short* __restrict__ Xe) {
  int b = blockIdx.x; int lane = threadIdx.x;
  int row = pref[b] + len[b] - 1;
  uint4 pk = *(const uint4*)(X + (size_t)row*DD + lane*8);
  float v[8];
  v[0]=bf2f(pk.x&0xffff); v[1]=bf2f(pk.x>>16);
  v[2]=bf2f(pk.y&0xffff); v[3]=bf2f(pk.y>>16);
  v[4]=bf2f(pk.z&0xffff); v[5]=bf2f(pk.z>>16);
  v[6]=bf2f(pk.w&0xffff); v[7]=bf2f(pk.w>>16);
  float s = 0.f, q = 0.f;
  #pragma unroll
  for (int i = 0; i < 8; ++i) { s += v[i]; q += v[i]*v[i]; }
  for (int off = 1; off < 64; off <<= 1) { s += __shfl_xor(s, off); q += __shfl_xor(q, off); }
  float mu = s * (1.f/DD);
  float var = q * (1.f/DD) - mu*mu;
  float rs = rsqrtf(var + 1e-5f);
  const float* wp = w + lane*8; const float* bp = bia + lane*8;
  float4 w0 = *(const float4*)wp;  float4 w1 = *(const float4*)(wp+4);
  float4 b0 = *(const float4*)bp;  float4 b1 = *(const float4*)(bp+4);
  float o0 = (v[0]-mu)*rs*w0.x + b0.x;
  float o1 = (v[1]-mu)*rs*w0.y + b0.y;
  float o2 = (v[2]-mu)*rs*w0.z + b0.z;
  float o3 = (v[3]-mu)*rs*w0.w + b0.w;
  float o4 = (v[4]-mu)*rs*w1.x + b1.x;
  float o5 = (v[5]-mu)*rs*w1.y + b1.y;
  float o6 = (v[6]-mu)*rs*w1.z + b1.z;
  float o7 = (v[7]-mu)*rs*w1.w + b1.w;
  uint4 ok; ok.x = pack2(o0,o1); ok.y = pack2(o2,o3); ok.z = pack2(o4,o5); ok.w = pack2(o6,o7);
  *(uint4*)(Xe + (size_t)b*DD + lane*8) = ok;
}

// ---------------- GEMM: C[M,N] = A[M,K] @ W[N,K]^T, BK=64, 32KB LDS, 4 blocks/CU ----------------
// R14 structure (best). mcp: compact-row early exit (nullptr = no check).
// EPI 0: bias->bf16. EPI 1: bias+gelu->bf16. EPI 2: residual RMW (LDS slab, uint4). EPI 3: f32.
template<int EPI>
__global__ __launch_bounds__(256, 4) void gemm_bt(
    const unsigned short* __restrict__ A,
    const unsigned short* __restrict__ W,
    const float* __restrict__ bias,
    unsigned short* __restrict__ Ob,
    float* __restrict__ Of,
    int N, int K, const int* __restrict__ mcp)
{
  __shared__ __align__(16) char smem[32768];      // As 16KB | Bs 16KB; epilogue slab aliases
  unsigned short* As = (unsigned short*)smem;
  unsigned short* Bs = (unsigned short*)(smem + 16384);
  int bx, by;
  xcd_remap(bx, by);
  const int m0 = by * 128, n0 = bx * 128;
  if (mcp && m0 >= *mcp) return;                  // dead token tile
  const int tid = threadIdx.x;
  const int lane = tid & 63;
  const int wid = tid >> 6;
  const int wr = wid >> 1, wc = wid & 1;

  f32x4 acc[4][4] = {};

  const int r0 = tid >> 3;                       // 0..31 (row within 32-row group)
  const int cb = (((tid & 7) ^ (r0 & 7)) * 8);   // swizzled source 16B-unit
  const unsigned voff = (unsigned)(r0 * K + cb); // per-thread, loop-invariant

  const int c = lane & 15, gq = lane >> 4;
  const int aBase = (wr*64 + c)*64;
  const int bBase = (wc*64 + c)*64;
  const int sw0 = ((0*4 + gq) ^ (c & 7)) * 8;
  const int sw1 = ((1*4 + gq) ^ (c & 7)) * 8;

  for (int k0 = 0; k0 < K; k0 += 64) {
    const unsigned short* pA = A + (size_t)m0 * K + k0;   // wave-uniform (SGPR)
    const unsigned short* pW = W + (size_t)n0 * K + k0;
    #pragma unroll
    for (int g = 0; g < 4; ++g) {
      gload16(pA + (size_t)g*32*K + voff, As + g*2048 + tid*8);
      gload16(pW + (size_t)g*32*K + voff, Bs + g*2048 + tid*8);
    }
    __syncthreads();
    #pragma unroll
    for (int kk = 0; kk < 2; ++kk) {
      const int sw = kk ? sw1 : sw0;
      bf16x8 af[4], bfr[4];
      #pragma unroll
      for (int mi = 0; mi < 4; ++mi)
        af[mi] = *(const bf16x8*)(As + aBase + sw + mi*1024);
      #pragma unroll
      for (int ni = 0; ni < 4; ++ni)
        bfr[ni] = *(const bf16x8*)(Bs + bBase + sw + ni*1024);
      #pragma unroll
      for (int mi = 0; mi < 4; ++mi)
        #pragma unroll
        for (int ni = 0; ni < 4; ++ni)
          acc[mi][ni] = __builtin_amdgcn_mfma_f32_16x16x32_bf16(af[mi], bfr[ni], acc[mi][ni], 0, 0, 0);
    }
    __syncthreads();
  }

  if constexpr (EPI == 2) {
    // per-wave private f32 slab [16][68] (pad 68 -> 2-way-free writes), 4352 B/wave
    float* slab = (float*)smem + wid*1088;
    const int rr = lane >> 3;            // 0..7
    const int c8 = (lane & 7) * 8;       // 0..56
    const int gcol = n0 + wc*64 + c8;
    float4 bq0 = *(const float4*)(bias + gcol);
    float4 bq1 = *(const float4*)(bias + gcol + 4);
    float badd[8] = {bq0.x,bq0.y,bq0.z,bq0.w,bq1.x,bq1.y,bq1.z,bq1.w};
    #pragma unroll
    for (int mi = 0; mi < 4; ++mi) {
      #pragma unroll
      for (int ni = 0; ni < 4; ++ni)
        #pragma unroll
        for (int j = 0; j < 4; ++j)
          slab[(gq*4 + j)*68 + ni*16 + c] = acc[mi][ni][j];
      #pragma unroll
      for (int q = 0; q < 2; ++q) {
        int r = q*8 + rr;
        int grow = m0 + wr*64 + mi*16 + r;
        size_t ix = (size_t)grow * N + gcol;
        uint4 old = *(const uint4*)(Ob + ix);
        float vv[8];
        #pragma unroll
        for (int i = 0; i < 8; ++i) vv[i] = slab[r*68 + c8 + i] + badd[i];
        unsigned ow[4] = {old.x, old.y, old.z, old.w};
        uint4 res; unsigned* rp = (unsigned*)&res;
        #pragma unroll
        for (int h = 0; h < 4; ++h) {
          float a0 = vv[h*2]   + bf2f((unsigned short)(ow[h] & 0xffff));
          float a1 = vv[h*2+1] + bf2f((unsigned short)(ow[h] >> 16));
          rp[h] = pack2(a0, a1);
        }
        *(uint4*)(Ob + ix) = res;      // 16B/lane coalesced full-line RMW
      }
    }
  } else {
    const int rbase = m0 + wr*64 + gq*4;
    const int cbase = n0 + wc*64 + c;
    #pragma unroll
    for (int mi = 0; mi < 4; ++mi) {
      #pragma unroll
      for (int ni = 0; ni < 4; ++ni) {
        int col = cbase + ni*16;
        float bv = 0.f;
        if constexpr (EPI != 3) bv = bias[col];
        #pragma unroll
        for (int j = 0; j < 4; ++j) {
          int row = rbase + mi*16 + j;
          float v = acc[mi][ni][j] + bv;
          size_t ix = (size_t)row*N + col;
          if constexpr (EPI == 0) {
            Ob[ix] = f2bf(v);
          } else if constexpr (EPI == 1) {
            float sg = 1.f/(1.f + __expf(-1.702f*v));
            Ob[ix] = f2bf(v*sg);
          } else {
            Of[ix] = v;
          }
        }
      }
    }
  }
}

// ---------------- MFMA attention: one block per (b,h), 5 waves, compact rows --------
// Stage only l < Lb (zeros beyond); skip dead strips and dead K-tiles (wave-uniform,
// static sc[] indexing). Bit-exact with full version for live rows (skipped terms = 0).
#define QS 72    // q/k LDS row stride (elems); +8 pad -> conflict-free frag reads
#define VS 104   // vt/p LDS row stride (elems)

__global__ __launch_bounds__(320) void attn_mfma(
    const unsigned short* __restrict__ qkv,   // [Mc][1536] compact bf16
    const int* __restrict__ len,
    const int* __restrict__ pref,
    unsigned short* __restrict__ O)           // [Mc][512] compact bf16
{
  __shared__ __align__(16) unsigned short q_s[80*QS];
  __shared__ __align__(16) unsigned short k_s[80*QS];
  __shared__ __align__(16) unsigned short vt_s[64*VS];
  __shared__ __align__(16) unsigned short p_s[80*VS];
  const int bh = blockIdx.x;
  const int b = bh >> 3, h = bh & 7;
  const int tid = threadIdx.x, lane = tid & 63, g = lane >> 4, c = lane & 15;
  const int Lb = len[b];
  const int pb = pref[b];
  const int nts = (Lb + 15) >> 4;           // live 16-col K-tiles (1..5)
  const size_t base = (size_t)pb*1536 + h*64;

  // Q/K: 8 bf16 per lane, coalesced; rows >= Lb zero
  for (int idx = tid; idx < 640; idx += 320) {    // 80 rows x 8 groups
    int l = idx >> 3, d8 = (idx & 7) * 8;
    uint4 qv = {0,0,0,0}, kv = {0,0,0,0};
    if (l < Lb) {
      const unsigned short* gp = qkv + base + (size_t)l*1536 + d8;
      qv = *(const uint4*)gp;
      kv = *(const uint4*)(gp + 512);
    }
    *(uint4*)(q_s + l*QS + d8) = qv;
    *(uint4*)(k_s + l*QS + d8) = kv;
  }
  // V transpose: contiguous LDS writes; rows >= Lb zero
  for (int idx = tid; idx < 64*96; idx += 320) {
    int d = idx / 96, l = idx % 96;
    vt_s[d*VS + l] = (l < Lb) ? qkv[base + (size_t)l*1536 + 1024 + d] : (unsigned short)0;
  }
  // zero p_s cols 0..95 (live cols overwritten below)
  {
    uint4 z = {0,0,0,0};
    for (int idx = tid; idx < 80*12; idx += 320) {
      int r = idx / 12, cblk = idx % 12;
      *(uint4*)(p_s + r*VS + cblk*8) = z;
    }
  }
  __syncthreads();

  const int s = tid >> 6;                   // one strip per wave, 0..4
  if (s*16 < Lb) {
    const int m0 = s*16;
    bf16x8 aq0 = *(const bf16x8*)(q_s + (m0 + c)*QS + g*8);
    bf16x8 aq1 = *(const bf16x8*)(q_s + (m0 + c)*QS + 32 + g*8);
    f32x4 sc[5];
    #pragma unroll
    for (int nt = 0; nt < 5; ++nt) {
      if (nt < nts) {                       // wave-uniform; static sc index
        bf16x8 bk0 = *(const bf16x8*)(k_s + (nt*16 + c)*QS + g*8);
        bf16x8 bk1 = *(const bf16x8*)(k_s + (nt*16 + c)*QS + 32 + g*8);
        f32x4 z = {};
        z = __builtin_amdgcn_mfma_f32_16x16x32_bf16(aq0, bk0, z, 0, 0, 0);
        sc[nt] = __builtin_amdgcn_mfma_f32_16x16x32_bf16(aq1, bk1, z, 0, 0, 0);
      } else {
        sc[nt] = f32x4{0.f, 0.f, 0.f, 0.f};
      }
    }
    #pragma unroll
    for (int j = 0; j < 4; ++j) {
      int r = m0 + g*4 + j;
      float sv[5];
      float mx = -3.4e38f;
      #pragma unroll
      for (int nt = 0; nt < 5; ++nt) {
        sv[nt] = (nt < nts) ? (sc[nt][j]*0.125f + maskv(r, nt*16 + c, Lb)) : -3.4e38f;
        mx = fmaxf(mx, sv[nt]);
      }
      mx = fmaxf(mx, __shfl_xor(mx, 1));
      mx = fmaxf(mx, __shfl_xor(mx, 2));
      mx = fmaxf(mx, __shfl_xor(mx, 4));
      mx = fmaxf(mx, __shfl_xor(mx, 8));
      float sum = 0.f;
      #pragma unroll
      for (int nt = 0; nt < 5; ++nt) { sv[nt] = __expf(sv[nt] - mx); sum += sv[nt]; }
      sum += __shfl_xor(sum, 1); sum += __shfl_xor(sum, 2);
      sum += __shfl_xor(sum, 4); sum += __shfl_xor(sum, 8);
      float inv = 1.f / sum;
      #pragma unroll
      for (int nt = 0; nt < 5; ++nt)
        if (nt < nts) p_s[r*VS + nt*16 + c] = f2bf(sv[nt] * inv);
    }
    f32x4 oa[4] = {};
    #pragma unroll
    for (int kk = 0; kk < 3; ++kk) {
      if (kk*32 < Lb) {                     // dead 32-col blocks: p and V are zero
        bf16x8 ap = *(const bf16x8*)(p_s + (m0 + c)*VS + kk*32 + g*8);
        #pragma unroll
        for (int nt = 0; nt < 4; ++nt) {
          bf16x8 bv = *(const bf16x8*)(vt_s + (nt*16 + c)*VS + kk*32 + g*8);
          oa[nt] = __builtin_amdgcn_mfma_f32_16x16x32_bf16(ap, bv, oa[nt], 0, 0, 0);
        }
      }
    }
    #pragma unroll
    for (int nt = 0; nt < 4; ++nt) {
      #pragma unroll
      for (int j = 0; j < 4; ++j) {
        int r = m0 + g*4 + j;
        if (r < Lb)
          O[((size_t)(pb + r))*512 + h*64 + nt*16 + c] = f2bf(oa[nt][j]);
      }
    }
  }
}

extern "C" void kernel_launch(void* const* d_in, const int* in_sizes, int n_in,
                              void* d_out, int out_size, void* d_ws, size_t ws_size,
                              hipStream_t stream) {
  const float* prompts = (const float*)d_in[0];
  const float* pos_emb = (const float*)d_in[1];
  const int*   tokens  = (const int*)d_in[2];
  const float* ln1w    = (const float*)d_in[3];
  const float* ln1b    = (const float*)d_in[4];
  const float* inw     = (const float*)d_in[5];
  const float* inb     = (const float*)d_in[6];
  const float* opw     = (const float*)d_in[7];
  const float* opb     = (const float*)d_in[8];
  const float* ln2w    = (const float*)d_in[9];
  const float* ln2b    = (const float*)d_in[10];
  const float* fcw     = (const float*)d_in[11];
  const float* fcb     = (const float*)d_in[12];
  const float* cpw     = (const float*)d_in[13];
  const float* cpb     = (const float*)d_in[14];
  const float* lnfw    = (const float*)d_in[15];
  const float* lnfb    = (const float*)d_in[16];
  const float* tp      = (const float*)d_in[17];
  float* out = (float*)d_out;

  char* basep = (char*)d_ws;
  size_t off = 0;
  auto carve = [&](size_t bytes) {
    char* p = basep + off;
    off += (bytes + 255) & ~(size_t)255;
    return (void*)p;
  };
  unsigned short* x   = (unsigned short*)carve((size_t)NTOK*DD*2);   // 40.4 MB (bf16 residual)
  unsigned short* hb  = (unsigned short*)carve((size_t)NTOK*DD*2);   // 40.4 MB
  unsigned short* w_tp = (unsigned short*)carve((size_t)512*512*2);
  unsigned short* xe   = (unsigned short*)carve((size_t)BB*DD*2);
  int* len             = (int*)carve((size_t)BB*4);
  int* pref            = (int*)carve((size_t)(BB+1)*4);
  int* mc              = (int*)carve((size_t)4);

  // ---- compaction requires nch=1 (big = full compact qkv/h2 buffer) ----
  const size_t per_layer_w = (size_t)(1536*512 + 512*512 + 2048*512 + 512*2048);
  size_t rem = (ws_size > off) ? (ws_size - off) : 0;
  const size_t big_b = (size_t)NTOK*2048*2 + 1024;
  const size_t wfull = per_layer_w * NLAYER * 2 + 2048;
  const size_t wrot  = per_layer_w * 2 + 2048;
  bool fullw;
  if      (rem >= big_b + wfull) { fullw = true; }
  else if (rem >= big_b + wrot)  { fullw = false; }
  else {
    diag_kernel<<<1, 1, 0, stream>>>(out, 1000.0f + (float)(ws_size >> 20));
    return;
  }

  unsigned short* big = (unsigned short*)carve((size_t)NTOK*2048*2);
  unsigned short *w_in, *w_op, *w_fc, *w_cp;
  size_t stride_in = (size_t)1536*512, stride_op = (size_t)512*512;
  size_t stride_fc = (size_t)2048*512, stride_cp = (size_t)512*2048;
  if (fullw) {
    w_in = (unsigned short*)carve(NLAYER*stride_in*2);
    w_op = (unsigned short*)carve(NLAYER*stride_op*2);
    w_fc = (unsigned short*)carve(NLAYER*stride_fc*2);
    w_cp = (unsigned short*)carve(NLAYER*stride_cp*2);
  } else {
    w_in = (unsigned short*)carve(stride_in*2);
    w_op = (unsigned short*)carve(stride_op*2);
    w_fc = (unsigned short*)carve(stride_fc*2);
    w_cp = (unsigned short*)carve(stride_cp*2);
    stride_in = stride_op = stride_fc = stride_cp = 0;
  }

  lengths_kernel<<<BB, 64, 0, stream>>>(tokens, len);
  scan_kernel<<<1, 512, 0, stream>>>(len, pref, mc);
  embed_kernel<<<NTOK, 128, 0, stream>>>((const float4*)prompts, (const float4*)pos_emb,
                                         len, pref, (uint2*)x);
  tpT_kernel<<<512, 256, 0, stream>>>(tp, w_tp);

  if (fullw) {
    cvt_kernel<<<4096, 256, 0, stream>>>((const float4*)inw, (uint2*)w_in, NLAYER*1536*512/4);
    cvt_kernel<<<4096, 256, 0, stream>>>((const float4*)opw, (uint2*)w_op, NLAYER*512*512/4);
    cvt_kernel<<<4096, 256, 0, stream>>>((const float4*)fcw, (uint2*)w_fc, NLAYER*2048*512/4);
    cvt_kernel<<<4096, 256, 0, stream>>>((const float4*)cpw, (uint2*)w_cp, NLAYER*512*2048/4);
  }

  for (int l = 0; l < NLAYER; ++l) {
    if (!fullw) {
      cvt_kernel<<<512, 256, 0, stream>>>((const float4*)(inw + (size_t)l*1536*512), (uint2*)w_in, 1536*512/4);
      cvt_kernel<<<512, 256, 0, stream>>>((const float4*)(opw + (size_t)l*512*512), (uint2*)w_op, 512*512/4);
      cvt_kernel<<<512, 256, 0, stream>>>((const float4*)(fcw + (size_t)l*2048*512), (uint2*)w_fc, 2048*512/4);
      cvt_kernel<<<512, 256, 0, stream>>>((const float4*)(cpw + (size_t)l*512*2048), (uint2*)w_cp, 512*2048/4);
    }
    const unsigned short* lw_in = w_in + (size_t)l*stride_in;
    const unsigned short* lw_op = w_op + (size_t)l*stride_op;
    const unsigned short* lw_fc = w_fc + (size_t)l*stride_fc;
    const unsigned short* lw_cp = w_cp + (size_t)l*stride_cp;

    ln_kernel<<<NTOK/4, 256, 0, stream>>>(x, ln1w + l*DD, ln1b + l*DD, hb, mc);
    gemm_bt<0><<<dim3(1536/128, NTOK/128), 256, 0, stream>>>(
        hb, lw_in, inb + l*1536, big, nullptr, 1536, 512, mc);
    attn_mfma<<<BB*HH, 320, 0, stream>>>(big, len, pref, hb);
    gemm_bt<2><<<dim3(512/128, NTOK/128), 256, 0, stream>>>(
        hb, lw_op, opb + l*DD, x, nullptr, 512, 512, mc);

    ln_kernel<<<NTOK/4, 256, 0, stream>>>(x, ln2w + l*DD, ln2b + l*DD, hb, mc);
    gemm_bt<1><<<dim3(2048/128, NTOK/128), 256, 0, stream>>>(
        hb, lw_fc, fcb + l*2048, big, nullptr, 2048, 512, mc);
    gemm_bt<2><<<dim3(512/128, NTOK/128), 256, 0, stream>>>(
        big, lw_cp, cpb + l*DD, x, nullptr, 512, 2048, mc);
  }

  eot_ln_kernel<<<BB, 64, 0, stream>>>(x, len, pref, lnfw, lnfb, xe);
  gemm_bt<3><<<dim3(512/128, 512/128), 256, 0, stream>>>(
      xe, w_tp, nullptr, nullptr, out, 512, 512, nullptr);
}

// Round 18
// 3710.062 us; speedup vs baseline: 1.4238x; 1.2643x over previous
//
#include <hip/hip_runtime.h>
#include <hip/hip_bf16.h>
#include <stdint.h>

#define BB 512
#define LL 77
#define DD 512
#define HH 8
#define NLAYER 12
#define NTOK (BB*LL)        // 39424 = 308*128

typedef __bf16 bf16x8 __attribute__((ext_vector_type(8)));
typedef float f32x4 __attribute__((ext_vector_type(4)));

__device__ inline unsigned short f2bf(float f) {
  unsigned u = __float_as_uint(f);
  u += 0x7fffu + ((u >> 16) & 1u);
  return (unsigned short)(u >> 16);
}
__device__ inline float bf2f(unsigned short s) {
  return __uint_as_float(((unsigned)s) << 16);
}
__device__ inline unsigned pack2(float a, float b) {
  return (unsigned)f2bf(a) | ((unsigned)f2bf(b) << 16);
}
__device__ inline void gload16(const void* g, void* l) {
  __builtin_amdgcn_global_load_lds(
      (const __attribute__((address_space(1))) void*)g,
      (__attribute__((address_space(3))) void*)l, 16, 0, 0);
}

__global__ void diag_kernel(float* out, float v) { out[0] = v; }

// ---------------- lengths = argmax(tokens)+1 ----------------
__global__ void lengths_kernel(const int* __restrict__ tok, int* __restrict__ len) {
  int b = blockIdx.x; int lane = threadIdx.x;
  int bv = -2147483647, bi = 0;
  for (int j = lane; j < LL; j += 64) {
    int v = tok[b*LL + j];
    if (v > bv) { bv = v; bi = j; }
  }
  for (int off = 32; off; off >>= 1) {
    int ov = __shfl_down(bv, off);
    int oi = __shfl_down(bi, off);
    if (ov > bv || (ov == bv && oi < bi)) { bv = ov; bi = oi; }
  }
  if (lane == 0) len[b] = bi + 1;
}

// ---------------- exclusive prefix over lengths + total Mc ----------------
__global__ void scan_kernel(const int* __restrict__ len, int* __restrict__ pref,
                            int* __restrict__ mc) {
  __shared__ int sm[512];
  int t = threadIdx.x;
  sm[t] = len[t];
  __syncthreads();
  for (int off = 1; off < 512; off <<= 1) {
    int v = (t >= off) ? sm[t - off] : 0;
    __syncthreads();
    sm[t] += v;
    __syncthreads();
  }
  pref[t + 1] = sm[t];
  if (t == 0) pref[0] = 0;
  if (t == 511) *mc = sm[511];
}

// ---------------- embed (compact gather): x[pref[b]+l] = bf16(prompts+pe) ----------------
__global__ void embed_kernel(const float4* __restrict__ p,
                             const float4* __restrict__ pe,
                             const int* __restrict__ len,
                             const int* __restrict__ pref,
                             uint2* __restrict__ x) {
  int r = blockIdx.x;
  int t = threadIdx.x;           // 0..127, 4 elems each
  int b = r / LL, l = r - b*LL;
  if (l >= len[b]) return;       // dead row
  float4 a = p[(size_t)r*128 + t];
  float4 bb = pe[(size_t)l*128 + t];
  uint2 o; o.x = pack2(a.x+bb.x, a.y+bb.y); o.y = pack2(a.z+bb.z, a.w+bb.w);
  x[(size_t)(pref[b] + l)*128 + t] = o;
}

// mask value per reference where-chain (P=1, C=10 -> [1,11))
__device__ inline float maskv(int i, int j, int Lb) {
  const float NEG = -1e30f;
  float m = (j > i) ? NEG : 0.f;
  bool ctx = (i >= 1 && i < 11);
  if (ctx && j < Lb) m = 0.f;
  if (i >= 11 && i < Lb && j >= 1 && j < 11) m = NEG;
  if (ctx && j >= 1 && j < 11) m = NEG;
  if (j >= Lb) m = NEG;
  bool eot = (i == Lb - 1);
  if (eot && j < 11) m = 0.f;
  if (eot && j >= 11 && j < Lb) m = 0.1f;
  return m;
}

// ---------------- f32 -> bf16 convert ----------------
__global__ void cvt_kernel(const float4* __restrict__ s, uint2* __restrict__ d, int n4) {
  for (int i = blockIdx.x*blockDim.x + threadIdx.x; i < n4; i += gridDim.x*blockDim.x) {
    float4 v = s[i];
    uint2 o; o.x = pack2(v.x, v.y); o.y = pack2(v.z, v.w);
    d[i] = o;
  }
}

// ---------------- transpose text_projection (D,PROJ) -> W[PROJ][D] bf16 ----------------
__global__ void tpT_kernel(const float* __restrict__ tp, unsigned short* __restrict__ W) {
  int p = blockIdx.x;
  for (int d = threadIdx.x; d < DD; d += 256)
    W[(size_t)p*DD + d] = f2bf(tp[(size_t)d*DD + p]);
}

// ---------------- LayerNorm row of 512 (bf16 in) -> bf16 out; compact rows < Mc --------
__global__ __launch_bounds__(256) void ln_kernel(const unsigned short* __restrict__ X,
    const float* __restrict__ w, const float* __restrict__ bia,
    unsigned short* __restrict__ Oh, const int* __restrict__ mcp) {
  int row = blockIdx.x*4 + (threadIdx.x >> 6);
  if (row >= *mcp) return;
  int lane = threadIdx.x & 63;
  uint4 pk = *(const uint4*)(X + (size_t)row*DD + lane*8);
  float v[8];
  v[0]=bf2f(pk.x&0xffff); v[1]=bf2f(pk.x>>16);
  v[2]=bf2f(pk.y&0xffff); v[3]=bf2f(pk.y>>16);
  v[4]=bf2f(pk.z&0xffff); v[5]=bf2f(pk.z>>16);
  v[6]=bf2f(pk.w&0xffff); v[7]=bf2f(pk.w>>16);
  float s = 0.f, q = 0.f;
  #pragma unroll
  for (int i = 0; i < 8; ++i) { s += v[i]; q += v[i]*v[i]; }
  for (int off = 1; off < 64; off <<= 1) { s += __shfl_xor(s, off); q += __shfl_xor(q, off); }
  float mu = s * (1.f/DD);
  float var = q * (1.f/DD) - mu*mu;
  float rs = rsqrtf(var + 1e-5f);
  const float* wp = w + lane*8; const float* bp = bia + lane*8;
  float4 w0 = *(const float4*)wp;  float4 w1 = *(const float4*)(wp+4);
  float4 b0 = *(const float4*)bp;  float4 b1 = *(const float4*)(bp+4);
  float o0 = (v[0]-mu)*rs*w0.x + b0.x;
  float o1 = (v[1]-mu)*rs*w0.y + b0.y;
  float o2 = (v[2]-mu)*rs*w0.z + b0.z;
  float o3 = (v[3]-mu)*rs*w0.w + b0.w;
  float o4 = (v[4]-mu)*rs*w1.x + b1.x;
  float o5 = (v[5]-mu)*rs*w1.y + b1.y;
  float o6 = (v[6]-mu)*rs*w1.z + b1.z;
  float o7 = (v[7]-mu)*rs*w1.w + b1.w;
  uint4 ok; ok.x = pack2(o0,o1); ok.y = pack2(o2,o3); ok.z = pack2(o4,o5); ok.w = pack2(o6,o7);
  *(uint4*)(Oh + (size_t)row*DD + lane*8) = ok;
}

// ---------------- final LN at eot row per batch (compact) ----------------
__global__ void eot_ln_kernel(const unsigned short* __restrict__ X, const int* __restrict__ len,
    const int* __restrict__ pref,
    const float* __restrict__ w, const float* __restrict__ bia,
    unsigned short* __restrict__ Xe) {
  int b = blockIdx.x; int lane = threadIdx.x;
  int row = pref[b] + len[b] - 1;
  uint4 pk = *(const uint4*)(X + (size_t)row*DD + lane*8);
  float v[8];
  v[0]=bf2f(pk.x&0xffff); v[1]=bf2f(pk.x>>16);
  v[2]=bf2f(pk.y&0xffff); v[3]=bf2f(pk.y>>16);
  v[4]=bf2f(pk.z&0xffff); v[5]=bf2f(pk.z>>16);
  v[6]=bf2f(pk.w&0xffff); v[7]=bf2f(pk.w>>16);
  float s = 0.f, q = 0.f;
  #pragma unroll
  for (int i = 0; i < 8; ++i) { s += v[i]; q += v[i]*v[i]; }
  for (int off = 1; off < 64; off <<= 1) { s += __shfl_xor(s, off); q += __shfl_xor(q, off); }
  float mu = s * (1.f/DD);
  float var = q * (1.f/DD) - mu*mu;
  float rs = rsqrtf(var + 1e-5f);
  const float* wp = w + lane*8; const float* bp = bia + lane*8;
  float4 w0 = *(const float4*)wp;  float4 w1 = *(const float4*)(wp+4);
  float4 b0 = *(const float4*)bp;  float4 b1 = *(const float4*)(bp+4);
  float o0 = (v[0]-mu)*rs*w0.x + b0.x;
  float o1 = (v[1]-mu)*rs*w0.y + b0.y;
  float o2 = (v[2]-mu)*rs*w0.z + b0.z;
  float o3 = (v[3]-mu)*rs*w0.w + b0.w;
  float o4 = (v[4]-mu)*rs*w1.x + b1.x;
  float o5 = (v[5]-mu)*rs*w1.y + b1.y;
  float o6 = (v[6]-mu)*rs*w1.z + b1.z;
  float o7 = (v[7]-mu)*rs*w1.w + b1.w;
  uint4 ok; ok.x = pack2(o0,o1); ok.y = pack2(o2,o3); ok.z = pack2(o4,o5); ok.w = pack2(o6,o7);
  *(uint4*)(Xe + (size_t)b*DD + lane*8) = ok;
}

// ---------------- GEMM: C[M,N] = A[M,K] @ W[N,K]^T, BK=64, 32KB LDS, 4 blocks/CU ----------------
// R18: NO xcd_remap — with early-exit compaction, the remap clustered all dead tiles
// onto XCDs 5-7 (flat&7>=5 -> nf>=Mc), idling 3/8 of the machine. Identity mapping
// round-robins dead tail tiles evenly across XCDs.
// EPI 0: bias->bf16. EPI 1: bias+gelu->bf16. EPI 2: residual RMW (LDS slab, uint4). EPI 3: f32.
template<int EPI>
__global__ __launch_bounds__(256, 4) void gemm_bt(
    const unsigned short* __restrict__ A,
    const unsigned short* __restrict__ W,
    const float* __restrict__ bias,
    unsigned short* __restrict__ Ob,
    float* __restrict__ Of,
    int N, int K, const int* __restrict__ mcp)
{
  __shared__ __align__(16) char smem[32768];      // As 16KB | Bs 16KB; epilogue slab aliases
  unsigned short* As = (unsigned short*)smem;
  unsigned short* Bs = (unsigned short*)(smem + 16384);
  const int bx = blockIdx.x, by = blockIdx.y;
  const int m0 = by * 128, n0 = bx * 128;
  if (mcp && m0 >= *mcp) return;                  // dead token tile
  const int tid = threadIdx.x;
  const int lane = tid & 63;
  const int wid = tid >> 6;
  const int wr = wid >> 1, wc = wid & 1;

  f32x4 acc[4][4] = {};

  const int r0 = tid >> 3;                       // 0..31 (row within 32-row group)
  const int cb = (((tid & 7) ^ (r0 & 7)) * 8);   // swizzled source 16B-unit
  const unsigned voff = (unsigned)(r0 * K + cb); // per-thread, loop-invariant

  const int c = lane & 15, gq = lane >> 4;
  const int aBase = (wr*64 + c)*64;
  const int bBase = (wc*64 + c)*64;
  const int sw0 = ((0*4 + gq) ^ (c & 7)) * 8;
  const int sw1 = ((1*4 + gq) ^ (c & 7)) * 8;

  for (int k0 = 0; k0 < K; k0 += 64) {
    const unsigned short* pA = A + (size_t)m0 * K + k0;   // wave-uniform (SGPR)
    const unsigned short* pW = W + (size_t)n0 * K + k0;
    #pragma unroll
    for (int g = 0; g < 4; ++g) {
      gload16(pA + (size_t)g*32*K + voff, As + g*2048 + tid*8);
      gload16(pW + (size_t)g*32*K + voff, Bs + g*2048 + tid*8);
    }
    __syncthreads();
    #pragma unroll
    for (int kk = 0; kk < 2; ++kk) {
      const int sw = kk ? sw1 : sw0;
      bf16x8 af[4], bfr[4];
      #pragma unroll
      for (int mi = 0; mi < 4; ++mi)
        af[mi] = *(const bf16x8*)(As + aBase + sw + mi*1024);
      #pragma unroll
      for (int ni = 0; ni < 4; ++ni)
        bfr[ni] = *(const bf16x8*)(Bs + bBase + sw + ni*1024);
      #pragma unroll
      for (int mi = 0; mi < 4; ++mi)
        #pragma unroll
        for (int ni = 0; ni < 4; ++ni)
          acc[mi][ni] = __builtin_amdgcn_mfma_f32_16x16x32_bf16(af[mi], bfr[ni], acc[mi][ni], 0, 0, 0);
    }
    __syncthreads();
  }

  if constexpr (EPI == 2) {
    // per-wave private f32 slab [16][68] (pad 68 -> 2-way-free writes), 4352 B/wave
    float* slab = (float*)smem + wid*1088;
    const int rr = lane >> 3;            // 0..7
    const int c8 = (lane & 7) * 8;       // 0..56
    const int gcol = n0 + wc*64 + c8;
    float4 bq0 = *(const float4*)(bias + gcol);
    float4 bq1 = *(const float4*)(bias + gcol + 4);
    float badd[8] = {bq0.x,bq0.y,bq0.z,bq0.w,bq1.x,bq1.y,bq1.z,bq1.w};
    #pragma unroll
    for (int mi = 0; mi < 4; ++mi) {
      #pragma unroll
      for (int ni = 0; ni < 4; ++ni)
        #pragma unroll
        for (int j = 0; j < 4; ++j)
          slab[(gq*4 + j)*68 + ni*16 + c] = acc[mi][ni][j];
      #pragma unroll
      for (int q = 0; q < 2; ++q) {
        int r = q*8 + rr;
        int grow = m0 + wr*64 + mi*16 + r;
        size_t ix = (size_t)grow * N + gcol;
        uint4 old = *(const uint4*)(Ob + ix);
        float vv[8];
        #pragma unroll
        for (int i = 0; i < 8; ++i) vv[i] = slab[r*68 + c8 + i] + badd[i];
        unsigned ow[4] = {old.x, old.y, old.z, old.w};
        uint4 res; unsigned* rp = (unsigned*)&res;
        #pragma unroll
        for (int h = 0; h < 4; ++h) {
          float a0 = vv[h*2]   + bf2f((unsigned short)(ow[h] & 0xffff));
          float a1 = vv[h*2+1] + bf2f((unsigned short)(ow[h] >> 16));
          rp[h] = pack2(a0, a1);
        }
        *(uint4*)(Ob + ix) = res;      // 16B/lane coalesced full-line RMW
      }
    }
  } else {
    const int rbase = m0 + wr*64 + gq*4;
    const int cbase = n0 + wc*64 + c;
    #pragma unroll
    for (int mi = 0; mi < 4; ++mi) {
      #pragma unroll
      for (int ni = 0; ni < 4; ++ni) {
        int col = cbase + ni*16;
        float bv = 0.f;
        if constexpr (EPI != 3) bv = bias[col];
        #pragma unroll
        for (int j = 0; j < 4; ++j) {
          int row = rbase + mi*16 + j;
          float v = acc[mi][ni][j] + bv;
          size_t ix = (size_t)row*N + col;
          if constexpr (EPI == 0) {
            Ob[ix] = f2bf(v);
          } else if constexpr (EPI == 1) {
            float sg = 1.f/(1.f + __expf(-1.702f*v));
            Ob[ix] = f2bf(v*sg);
          } else {
            Of[ix] = v;
          }
        }
      }
    }
  }
}

// ---------------- MFMA attention: one block per (b,h), 5 waves, compact rows --------
#define QS 72    // q/k LDS row stride (elems); +8 pad -> conflict-free frag reads
#define VS 104   // vt/p LDS row stride (elems)

__global__ __launch_bounds__(320) void attn_mfma(
    const unsigned short* __restrict__ qkv,   // [Mc][1536] compact bf16
    const int* __restrict__ len,
    const int* __restrict__ pref,
    unsigned short* __restrict__ O)           // [Mc][512] compact bf16
{
  __shared__ __align__(16) unsigned short q_s[80*QS];
  __shared__ __align__(16) unsigned short k_s[80*QS];
  __shared__ __align__(16) unsigned short vt_s[64*VS];
  __shared__ __align__(16) unsigned short p_s[80*VS];
  const int bh = blockIdx.x;
  const int b = bh >> 3, h = bh & 7;
  const int tid = threadIdx.x, lane = tid & 63, g = lane >> 4, c = lane & 15;
  const int Lb = len[b];
  const int pb = pref[b];
  const int nts = (Lb + 15) >> 4;           // live 16-col K-tiles (1..5)
  const size_t base = (size_t)pb*1536 + h*64;

  for (int idx = tid; idx < 640; idx += 320) {    // 80 rows x 8 groups
    int l = idx >> 3, d8 = (idx & 7) * 8;
    uint4 qv = {0,0,0,0}, kv = {0,0,0,0};
    if (l < Lb) {
      const unsigned short* gp = qkv + base + (size_t)l*1536 + d8;
      qv = *(const uint4*)gp;
      kv = *(const uint4*)(gp + 512);
    }
    *(uint4*)(q_s + l*QS + d8) = qv;
    *(uint4*)(k_s + l*QS + d8) = kv;
  }
  for (int idx = tid; idx < 64*96; idx += 320) {
    int d = idx / 96, l = idx % 96;
    vt_s[d*VS + l] = (l < Lb) ? qkv[base + (size_t)l*1536 + 1024 + d] : (unsigned short)0;
  }
  {
    uint4 z = {0,0,0,0};
    for (int idx = tid; idx < 80*12; idx += 320) {
      int r = idx / 12, cblk = idx % 12;
      *(uint4*)(p_s + r*VS + cblk*8) = z;
    }
  }
  __syncthreads();

  const int s = tid >> 6;                   // one strip per wave, 0..4
  if (s*16 < Lb) {
    const int m0 = s*16;
    bf16x8 aq0 = *(const bf16x8*)(q_s + (m0 + c)*QS + g*8);
    bf16x8 aq1 = *(const bf16x8*)(q_s + (m0 + c)*QS + 32 + g*8);
    f32x4 sc[5];
    #pragma unroll
    for (int nt = 0; nt < 5; ++nt) {
      if (nt < nts) {                       // wave-uniform; static sc index
        bf16x8 bk0 = *(const bf16x8*)(k_s + (nt*16 + c)*QS + g*8);
        bf16x8 bk1 = *(const bf16x8*)(k_s + (nt*16 + c)*QS + 32 + g*8);
        f32x4 z = {};
        z = __builtin_amdgcn_mfma_f32_16x16x32_bf16(aq0, bk0, z, 0, 0, 0);
        sc[nt] = __builtin_amdgcn_mfma_f32_16x16x32_bf16(aq1, bk1, z, 0, 0, 0);
      } else {
        sc[nt] = f32x4{0.f, 0.f, 0.f, 0.f};
      }
    }
    #pragma unroll
    for (int j = 0; j < 4; ++j) {
      int r = m0 + g*4 + j;
      float sv[5];
      float mx = -3.4e38f;
      #pragma unroll
      for (int nt = 0; nt < 5; ++nt) {
        sv[nt] = (nt < nts) ? (sc[nt][j]*0.125f + maskv(r, nt*16 + c, Lb)) : -3.4e38f;
        mx = fmaxf(mx, sv[nt]);
      }
      mx = fmaxf(mx, __shfl_xor(mx, 1));
      mx = fmaxf(mx, __shfl_xor(mx, 2));
      mx = fmaxf(mx, __shfl_xor(mx, 4));
      mx = fmaxf(mx, __shfl_xor(mx, 8));
      float sum = 0.f;
      #pragma unroll
      for (int nt = 0; nt < 5; ++nt) { sv[nt] = __expf(sv[nt] - mx); sum += sv[nt]; }
      sum += __shfl_xor(sum, 1); sum += __shfl_xor(sum, 2);
      sum += __shfl_xor(sum, 4); sum += __shfl_xor(sum, 8);
      float inv = 1.f / sum;
      #pragma unroll
      for (int nt = 0; nt < 5; ++nt)
        if (nt < nts) p_s[r*VS + nt*16 + c] = f2bf(sv[nt] * inv);
    }
    f32x4 oa[4] = {};
    #pragma unroll
    for (int kk = 0; kk < 3; ++kk) {
      if (kk*32 < Lb) {                     // dead 32-col blocks: p and V are zero
        bf16x8 ap = *(const bf16x8*)(p_s + (m0 + c)*VS + kk*32 + g*8);
        #pragma unroll
        for (int nt = 0; nt < 4; ++nt) {
          bf16x8 bv = *(const bf16x8*)(vt_s + (nt*16 + c)*VS + kk*32 + g*8);
          oa[nt] = __builtin_amdgcn_mfma_f32_16x16x32_bf16(ap, bv, oa[nt], 0, 0, 0);
        }
      }
    }
    #pragma unroll
    for (int nt = 0; nt < 4; ++nt) {
      #pragma unroll
      for (int j = 0; j < 4; ++j) {
        int r = m0 + g*4 + j;
        if (r < Lb)
          O[((size_t)(pb + r))*512 + h*64 + nt*16 + c] = f2bf(oa[nt][j]);
      }
    }
  }
}

extern "C" void kernel_launch(void* const* d_in, const int* in_sizes, int n_in,
                              void* d_out, int out_size, void* d_ws, size_t ws_size,
                              hipStream_t stream) {
  const float* prompts = (const float*)d_in[0];
  const float* pos_emb = (const float*)d_in[1];
  const int*   tokens  = (const int*)d_in[2];
  const float* ln1w    = (const float*)d_in[3];
  const float* ln1b    = (const float*)d_in[4];
  const float* inw     = (const float*)d_in[5];
  const float* inb     = (const float*)d_in[6];
  const float* opw     = (const float*)d_in[7];
  const float* opb     = (const float*)d_in[8];
  const float* ln2w    = (const float*)d_in[9];
  const float* ln2b    = (const float*)d_in[10];
  const float* fcw     = (const float*)d_in[11];
  const float* fcb     = (const float*)d_in[12];
  const float* cpw     = (const float*)d_in[13];
  const float* cpb     = (const float*)d_in[14];
  const float* lnfw    = (const float*)d_in[15];
  const float* lnfb    = (const float*)d_in[16];
  const float* tp      = (const float*)d_in[17];
  float* out = (float*)d_out;

  char* basep = (char*)d_ws;
  size_t off = 0;
  auto carve = [&](size_t bytes) {
    char* p = basep + off;
    off += (bytes + 255) & ~(size_t)255;
    return (void*)p;
  };
  unsigned short* x   = (unsigned short*)carve((size_t)NTOK*DD*2);   // 40.4 MB (bf16 residual)
  unsigned short* hb  = (unsigned short*)carve((size_t)NTOK*DD*2);   // 40.4 MB
  unsigned short* w_tp = (unsigned short*)carve((size_t)512*512*2);
  unsigned short* xe   = (unsigned short*)carve((size_t)BB*DD*2);
  int* len             = (int*)carve((size_t)BB*4);
  int* pref            = (int*)carve((size_t)(BB+1)*4);
  int* mc              = (int*)carve((size_t)4);

  // ---- compaction requires nch=1 (big = full compact qkv/h2 buffer) ----
  const size_t per_layer_w = (size_t)(1536*512 + 512*512 + 2048*512 + 512*2048);
  size_t rem = (ws_size > off) ? (ws_size - off) : 0;
  const size_t big_b = (size_t)NTOK*2048*2 + 1024;
  const size_t wfull = per_layer_w * NLAYER * 2 + 2048;
  const size_t wrot  = per_layer_w * 2 + 2048;
  bool fullw;
  if      (rem >= big_b + wfull) { fullw = true; }
  else if (rem >= big_b + wrot)  { fullw = false; }
  else {
    diag_kernel<<<1, 1, 0, stream>>>(out, 1000.0f + (float)(ws_size >> 20));
    return;
  }

  unsigned short* big = (unsigned short*)carve((size_t)NTOK*2048*2);
  unsigned short *w_in, *w_op, *w_fc, *w_cp;
  size_t stride_in = (size_t)1536*512, stride_op = (size_t)512*512;
  size_t stride_fc = (size_t)2048*512, stride_cp = (size_t)512*2048;
  if (fullw) {
    w_in = (unsigned short*)carve(NLAYER*stride_in*2);
    w_op = (unsigned short*)carve(NLAYER*stride_op*2);
    w_fc = (unsigned short*)carve(NLAYER*stride_fc*2);
    w_cp = (unsigned short*)carve(NLAYER*stride_cp*2);
  } else {
    w_in = (unsigned short*)carve(stride_in*2);
    w_op = (unsigned short*)carve(stride_op*2);
    w_fc = (unsigned short*)carve(stride_fc*2);
    w_cp = (unsigned short*)carve(stride_cp*2);
    stride_in = stride_op = stride_fc = stride_cp = 0;
  }

  lengths_kernel<<<BB, 64, 0, stream>>>(tokens, len);
  scan_kernel<<<1, 512, 0, stream>>>(len, pref, mc);
  embed_kernel<<<NTOK, 128, 0, stream>>>((const float4*)prompts, (const float4*)pos_emb,
                                         len, pref, (uint2*)x);
  tpT_kernel<<<512, 256, 0, stream>>>(tp, w_tp);

  if (fullw) {
    cvt_kernel<<<4096, 256, 0, stream>>>((const float4*)inw, (uint2*)w_in, NLAYER*1536*512/4);
    cvt_kernel<<<4096, 256, 0, stream>>>((const float4*)opw, (uint2*)w_op, NLAYER*512*512/4);
    cvt_kernel<<<4096, 256, 0, stream>>>((const float4*)fcw, (uint2*)w_fc, NLAYER*2048*512/4);
    cvt_kernel<<<4096, 256, 0, stream>>>((const float4*)cpw, (uint2*)w_cp, NLAYER*512*2048/4);
  }

  for (int l = 0; l < NLAYER; ++l) {
    if (!fullw) {
      cvt_kernel<<<512, 256, 0, stream>>>((const float4*)(inw + (size_t)l*1536*512), (uint2*)w_in, 1536*512/4);
      cvt_kernel<<<512, 256, 0, stream>>>((const float4*)(opw + (size_t)l*512*512), (uint2*)w_op, 512*512/4);
      cvt_kernel<<<512, 256, 0, stream>>>((const float4*)(fcw + (size_t)l*2048*512), (uint2*)w_fc, 2048*512/4);
      cvt_kernel<<<512, 256, 0, stream>>>((const float4*)(cpw + (size_t)l*512*2048), (uint2*)w_cp, 512*2048/4);
    }
    const unsigned short* lw_in = w_in + (size_t)l*stride_in;
    const unsigned short* lw_op = w_op + (size_t)l*stride_op;
    const unsigned short* lw_fc = w_fc + (size_t)l*stride_fc;
    const unsigned short* lw_cp = w_cp + (size_t)l*stride_cp;

    ln_kernel<<<NTOK/4, 256, 0, stream>>>(x, ln1w + l*DD, ln1b + l*DD, hb, mc);
    gemm_bt<0><<<dim3(1536/128, NTOK/128), 256, 0, stream>>>(
        hb, lw_in, inb + l*1536, big, nullptr, 1536, 512, mc);
    attn_mfma<<<BB*HH, 320, 0, stream>>>(big, len, pref, hb);
    gemm_bt<2><<<dim3(512/128, NTOK/128), 256, 0, stream>>>(
        hb, lw_op, opb + l*DD, x, nullptr, 512, 512, mc);

    ln_kernel<<<NTOK/4, 256, 0, stream>>>(x, ln2w + l*DD, ln2b + l*DD, hb, mc);
    gemm_bt<1><<<dim3(2048/128, NTOK/128), 256, 0, stream>>>(
        hb, lw_fc, fcb + l*2048, big, nullptr, 2048, 512, mc);
    gemm_bt<2><<<dim3(512/128, NTOK/128), 256, 0, stream>>>(
        big, lw_cp, cpb + l*DD, x, nullptr, 512, 2048, mc);
  }

  eot_ln_kernel<<<BB, 64, 0, stream>>>(x, len, pref, lnfw, lnfb, xe);
  gemm_bt<3><<<dim3(512/128, 512/128), 256, 0, stream>>>(
      xe, w_tp, nullptr, nullptr, out, 512, 512, nullptr);
}

// Round 19
// 3446.165 us; speedup vs baseline: 1.5328x; 1.0766x over previous
//
#include <hip/hip_runtime.h>
#include <hip/hip_bf16.h>
#include <stdint.h>

#define BB 512
#define LL 77
#define DD 512
#define HH 8
#define NLAYER 12
#define NTOK (BB*LL)        // 39424 = 308*128

typedef __bf16 bf16x8 __attribute__((ext_vector_type(8)));
typedef float f32x4 __attribute__((ext_vector_type(4)));

__device__ inline unsigned short f2bf(float f) {
  unsigned u = __float_as_uint(f);
  u += 0x7fffu + ((u >> 16) & 1u);
  return (unsigned short)(u >> 16);
}
__device__ inline float bf2f(unsigned short s) {
  return __uint_as_float(((unsigned)s) << 16);
}
__device__ inline unsigned pack2(float a, float b) {
  return (unsigned)f2bf(a) | ((unsigned)f2bf(b) << 16);
}
__device__ inline void gload16(const void* g, void* l) {
  __builtin_amdgcn_global_load_lds(
      (const __attribute__((address_space(1))) void*)g,
      (__attribute__((address_space(3))) void*)l, 16, 0, 0);
}

__global__ void diag_kernel(float* out, float v) { out[0] = v; }

// ---------------- lengths = argmax(tokens)+1 ----------------
__global__ void lengths_kernel(const int* __restrict__ tok, int* __restrict__ len) {
  int b = blockIdx.x; int lane = threadIdx.x;
  int bv = -2147483647, bi = 0;
  for (int j = lane; j < LL; j += 64) {
    int v = tok[b*LL + j];
    if (v > bv) { bv = v; bi = j; }
  }
  for (int off = 32; off; off >>= 1) {
    int ov = __shfl_down(bv, off);
    int oi = __shfl_down(bi, off);
    if (ov > bv || (ov == bv && oi < bi)) { bv = ov; bi = oi; }
  }
  if (lane == 0) len[b] = bi + 1;
}

// ---------------- exclusive prefix over lengths + total Mc ----------------
__global__ void scan_kernel(const int* __restrict__ len, int* __restrict__ pref,
                            int* __restrict__ mc) {
  __shared__ int sm[512];
  int t = threadIdx.x;
  sm[t] = len[t];
  __syncthreads();
  for (int off = 1; off < 512; off <<= 1) {
    int v = (t >= off) ? sm[t - off] : 0;
    __syncthreads();
    sm[t] += v;
    __syncthreads();
  }
  pref[t + 1] = sm[t];
  if (t == 0) pref[0] = 0;
  if (t == 511) *mc = sm[511];
}

// ---------------- embed (compact gather): x[pref[b]+l] = bf16(prompts+pe) ----------------
__global__ void embed_kernel(const float4* __restrict__ p,
                             const float4* __restrict__ pe,
                             const int* __restrict__ len,
                             const int* __restrict__ pref,
                             uint2* __restrict__ x) {
  int r = blockIdx.x;
  int t = threadIdx.x;           // 0..127, 4 elems each
  int b = r / LL, l = r - b*LL;
  if (l >= len[b]) return;       // dead row
  float4 a = p[(size_t)r*128 + t];
  float4 bb = pe[(size_t)l*128 + t];
  uint2 o; o.x = pack2(a.x+bb.x, a.y+bb.y); o.y = pack2(a.z+bb.z, a.w+bb.w);
  x[(size_t)(pref[b] + l)*128 + t] = o;
}

// mask value per reference where-chain (P=1, C=10 -> [1,11))
__device__ inline float maskv(int i, int j, int Lb) {
  const float NEG = -1e30f;
  float m = (j > i) ? NEG : 0.f;
  bool ctx = (i >= 1 && i < 11);
  if (ctx && j < Lb) m = 0.f;
  if (i >= 11 && i < Lb && j >= 1 && j < 11) m = NEG;
  if (ctx && j >= 1 && j < 11) m = NEG;
  if (j >= Lb) m = NEG;
  bool eot = (i == Lb - 1);
  if (eot && j < 11) m = 0.f;
  if (eot && j >= 11 && j < Lb) m = 0.1f;
  return m;
}

// ---------------- f32 -> bf16 convert ----------------
__global__ void cvt_kernel(const float4* __restrict__ s, uint2* __restrict__ d, int n4) {
  for (int i = blockIdx.x*blockDim.x + threadIdx.x; i < n4; i += gridDim.x*blockDim.x) {
    float4 v = s[i];
    uint2 o; o.x = pack2(v.x, v.y); o.y = pack2(v.z, v.w);
    d[i] = o;
  }
}

// ---------------- transpose text_projection (D,PROJ) -> W[PROJ][D] bf16 ----------------
__global__ void tpT_kernel(const float* __restrict__ tp, unsigned short* __restrict__ W) {
  int p = blockIdx.x;
  for (int d = threadIdx.x; d < DD; d += 256)
    W[(size_t)p*DD + d] = f2bf(tp[(size_t)d*DD + p]);
}

// ---------------- LayerNorm row of 512 (bf16 in) -> bf16 out; compact rows < Mc --------
__global__ __launch_bounds__(256) void ln_kernel(const unsigned short* __restrict__ X,
    const float* __restrict__ w, const float* __restrict__ bia,
    unsigned short* __restrict__ Oh, const int* __restrict__ mcp) {
  int row = blockIdx.x*4 + (threadIdx.x >> 6);
  if (row >= *mcp) return;
  int lane = threadIdx.x & 63;
  uint4 pk = *(const uint4*)(X + (size_t)row*DD + lane*8);
  float v[8];
  v[0]=bf2f(pk.x&0xffff); v[1]=bf2f(pk.x>>16);
  v[2]=bf2f(pk.y&0xffff); v[3]=bf2f(pk.y>>16);
  v[4]=bf2f(pk.z&0xffff); v[5]=bf2f(pk.z>>16);
  v[6]=bf2f(pk.w&0xffff); v[7]=bf2f(pk.w>>16);
  float s = 0.f, q = 0.f;
  #pragma unroll
  for (int i = 0; i < 8; ++i) { s += v[i]; q += v[i]*v[i]; }
  for (int off = 1; off < 64; off <<= 1) { s += __shfl_xor(s, off); q += __shfl_xor(q, off); }
  float mu = s * (1.f/DD);
  float var = q * (1.f/DD) - mu*mu;
  float rs = rsqrtf(var + 1e-5f);
  const float* wp = w + lane*8; const float* bp = bia + lane*8;
  float4 w0 = *(const float4*)wp;  float4 w1 = *(const float4*)(wp+4);
  float4 b0 = *(const float4*)bp;  float4 b1 = *(const float4*)(bp+4);
  float o0 = (v[0]-mu)*rs*w0.x + b0.x;
  float o1 = (v[1]-mu)*rs*w0.y + b0.y;
  float o2 = (v[2]-mu)*rs*w0.z + b0.z;
  float o3 = (v[3]-mu)*rs*w0.w + b0.w;
  float o4 = (v[4]-mu)*rs*w1.x + b1.x;
  float o5 = (v[5]-mu)*rs*w1.y + b1.y;
  float o6 = (v[6]-mu)*rs*w1.z + b1.z;
  float o7 = (v[7]-mu)*rs*w1.w + b1.w;
  uint4 ok; ok.x = pack2(o0,o1); ok.y = pack2(o2,o3); ok.z = pack2(o4,o5); ok.w = pack2(o6,o7);
  *(uint4*)(Oh + (size_t)row*DD + lane*8) = ok;
}

// ---------------- final LN at eot row per batch (compact) ----------------
__global__ void eot_ln_kernel(const unsigned short* __restrict__ X, const int* __restrict__ len,
    const int* __restrict__ pref,
    const float* __restrict__ w, const float* __restrict__ bia,
    unsigned short* __restrict__ Xe) {
  int b = blockIdx.x; int lane = threadIdx.x;
  int row = pref[b] + len[b] - 1;
  uint4 pk = *(const uint4*)(X + (size_t)row*DD + lane*8);
  float v[8];
  v[0]=bf2f(pk.x&0xffff); v[1]=bf2f(pk.x>>16);
  v[2]=bf2f(pk.y&0xffff); v[3]=bf2f(pk.y>>16);
  v[4]=bf2f(pk.z&0xffff); v[5]=bf2f(pk.z>>16);
  v[6]=bf2f(pk.w&0xffff); v[7]=bf2f(pk.w>>16);
  float s = 0.f, q = 0.f;
  #pragma unroll
  for (int i = 0; i < 8; ++i) { s += v[i]; q += v[i]*v[i]; }
  for (int off = 1; off < 64; off <<= 1) { s += __shfl_xor(s, off); q += __shfl_xor(q, off); }
  float mu = s * (1.f/DD);
  float var = q * (1.f/DD) - mu*mu;
  float rs = rsqrtf(var + 1e-5f);
  const float* wp = w + lane*8; const float* bp = bia + lane*8;
  float4 w0 = *(const float4*)wp;  float4 w1 = *(const float4*)(wp+4);
  float4 b0 = *(const float4*)bp;  float4 b1 = *(const float4*)(bp+4);
  float o0 = (v[0]-mu)*rs*w0.x + b0.x;
  float o1 = (v[1]-mu)*rs*w0.y + b0.y;
  float o2 = (v[2]-mu)*rs*w0.z + b0.z;
  float o3 = (v[3]-mu)*rs*w0.w + b0.w;
  float o4 = (v[4]-mu)*rs*w1.x + b1.x;
  float o5 = (v[5]-mu)*rs*w1.y + b1.y;
  float o6 = (v[6]-mu)*rs*w1.z + b1.z;
  float o7 = (v[7]-mu)*rs*w1.w + b1.w;
  uint4 ok; ok.x = pack2(o0,o1); ok.y = pack2(o2,o3); ok.z = pack2(o4,o5); ok.w = pack2(o6,o7);
  *(uint4*)(Xe + (size_t)b*DD + lane*8) = ok;
}

// ---------------- GEMM: C[M,N] = A[M,K] @ W[N,K]^T, BK=64, 32KB LDS, 4 blocks/CU ----------------
// No xcd_remap (dead-tile early-exit needs round-robin flat dispatch across XCDs).
// EPI 0: bias->bf16. EPI 1: bias+gelu->bf16. EPI 2: residual RMW (LDS slab, uint4). EPI 3: f32.
template<int EPI>
__global__ __launch_bounds__(256, 4) void gemm_bt(
    const unsigned short* __restrict__ A,
    const unsigned short* __restrict__ W,
    const float* __restrict__ bias,
    unsigned short* __restrict__ Ob,
    float* __restrict__ Of,
    int N, int K, const int* __restrict__ mcp)
{
  __shared__ __align__(16) char smem[32768];      // As 16KB | Bs 16KB; epilogue slab aliases
  unsigned short* As = (unsigned short*)smem;
  unsigned short* Bs = (unsigned short*)(smem + 16384);
  const int bx = blockIdx.x, by = blockIdx.y;
  const int m0 = by * 128, n0 = bx * 128;
  if (mcp && m0 >= *mcp) return;                  // dead token tile
  const int tid = threadIdx.x;
  const int lane = tid & 63;
  const int wid = tid >> 6;
  const int wr = wid >> 1, wc = wid & 1;

  f32x4 acc[4][4] = {};

  const int r0 = tid >> 3;                       // 0..31 (row within 32-row group)
  const int cb = (((tid & 7) ^ (r0 & 7)) * 8);   // swizzled source 16B-unit
  const unsigned voff = (unsigned)(r0 * K + cb); // per-thread, loop-invariant

  const int c = lane & 15, gq = lane >> 4;
  const int aBase = (wr*64 + c)*64;
  const int bBase = (wc*64 + c)*64;
  const int sw0 = ((0*4 + gq) ^ (c & 7)) * 8;
  const int sw1 = ((1*4 + gq) ^ (c & 7)) * 8;

  for (int k0 = 0; k0 < K; k0 += 64) {
    const unsigned short* pA = A + (size_t)m0 * K + k0;   // wave-uniform (SGPR)
    const unsigned short* pW = W + (size_t)n0 * K + k0;
    #pragma unroll
    for (int g = 0; g < 4; ++g) {
      gload16(pA + (size_t)g*32*K + voff, As + g*2048 + tid*8);
      gload16(pW + (size_t)g*32*K + voff, Bs + g*2048 + tid*8);
    }
    __syncthreads();
    #pragma unroll
    for (int kk = 0; kk < 2; ++kk) {
      const int sw = kk ? sw1 : sw0;
      bf16x8 af[4], bfr[4];
      #pragma unroll
      for (int mi = 0; mi < 4; ++mi)
        af[mi] = *(const bf16x8*)(As + aBase + sw + mi*1024);
      #pragma unroll
      for (int ni = 0; ni < 4; ++ni)
        bfr[ni] = *(const bf16x8*)(Bs + bBase + sw + ni*1024);
      #pragma unroll
      for (int mi = 0; mi < 4; ++mi)
        #pragma unroll
        for (int ni = 0; ni < 4; ++ni)
          acc[mi][ni] = __builtin_amdgcn_mfma_f32_16x16x32_bf16(af[mi], bfr[ni], acc[mi][ni], 0, 0, 0);
    }
    __syncthreads();
  }

  if constexpr (EPI == 2) {
    // per-wave private f32 slab [16][68] (pad 68 -> 2-way-free writes), 4352 B/wave
    float* slab = (float*)smem + wid*1088;
    const int rr = lane >> 3;            // 0..7
    const int c8 = (lane & 7) * 8;       // 0..56
    const int gcol = n0 + wc*64 + c8;
    float4 bq0 = *(const float4*)(bias + gcol);
    float4 bq1 = *(const float4*)(bias + gcol + 4);
    float badd[8] = {bq0.x,bq0.y,bq0.z,bq0.w,bq1.x,bq1.y,bq1.z,bq1.w};
    #pragma unroll
    for (int mi = 0; mi < 4; ++mi) {
      #pragma unroll
      for (int ni = 0; ni < 4; ++ni)
        #pragma unroll
        for (int j = 0; j < 4; ++j)
          slab[(gq*4 + j)*68 + ni*16 + c] = acc[mi][ni][j];
      #pragma unroll
      for (int q = 0; q < 2; ++q) {
        int r = q*8 + rr;
        int grow = m0 + wr*64 + mi*16 + r;
        size_t ix = (size_t)grow * N + gcol;
        uint4 old = *(const uint4*)(Ob + ix);
        float vv[8];
        #pragma unroll
        for (int i = 0; i < 8; ++i) vv[i] = slab[r*68 + c8 + i] + badd[i];
        unsigned ow[4] = {old.x, old.y, old.z, old.w};
        uint4 res; unsigned* rp = (unsigned*)&res;
        #pragma unroll
        for (int h = 0; h < 4; ++h) {
          float a0 = vv[h*2]   + bf2f((unsigned short)(ow[h] & 0xffff));
          float a1 = vv[h*2+1] + bf2f((unsigned short)(ow[h] >> 16));
          rp[h] = pack2(a0, a1);
        }
        *(uint4*)(Ob + ix) = res;      // 16B/lane coalesced full-line RMW
      }
    }
  } else {
    const int rbase = m0 + wr*64 + gq*4;
    const int cbase = n0 + wc*64 + c;
    #pragma unroll
    for (int mi = 0; mi < 4; ++mi) {
      #pragma unroll
      for (int ni = 0; ni < 4; ++ni) {
        int col = cbase + ni*16;
        float bv = 0.f;
        if constexpr (EPI != 3) bv = bias[col];
        #pragma unroll
        for (int j = 0; j < 4; ++j) {
          int row = rbase + mi*16 + j;
          float v = acc[mi][ni][j] + bv;
          size_t ix = (size_t)row*N + col;
          if constexpr (EPI == 0) {
            Ob[ix] = f2bf(v);
          } else if constexpr (EPI == 1) {
            float sg = 1.f/(1.f + __expf(-1.702f*v));
            Ob[ix] = f2bf(v*sg);
          } else {
            Of[ix] = v;
          }
        }
      }
    }
  }
}

// ---------------- MFMA attention: one block per (b,h), 5 waves, compact rows --------
// R19: V staged with COALESCED uint4 global reads (8 lanes/row -> ~4x fewer L2 lines
// than the old per-element gather) + XOR-swizzled LDS scatter (unit ^= (d>>3)&3,
// <=2-way banks). PV reads apply the same XOR (involution -> bit-exact).
#define QS 72    // q/k LDS row stride (elems); +8 pad -> conflict-free frag reads
#define VS 104   // vt/p LDS row stride (elems); 13 units of 8 (swizzle uses units 0..11^0..3)

__global__ __launch_bounds__(320) void attn_mfma(
    const unsigned short* __restrict__ qkv,   // [Mc][1536] compact bf16
    const int* __restrict__ len,
    const int* __restrict__ pref,
    unsigned short* __restrict__ O)           // [Mc][512] compact bf16
{
  __shared__ __align__(16) unsigned short q_s[80*QS];
  __shared__ __align__(16) unsigned short k_s[80*QS];
  __shared__ __align__(16) unsigned short vt_s[64*VS];
  __shared__ __align__(16) unsigned short p_s[80*VS];
  const int bh = blockIdx.x;
  const int b = bh >> 3, h = bh & 7;
  const int tid = threadIdx.x, lane = tid & 63, g = lane >> 4, c = lane & 15;
  const int Lb = len[b];
  const int pb = pref[b];
  const int nts = (Lb + 15) >> 4;           // live 16-col K-tiles (1..5)
  const size_t base = (size_t)pb*1536 + h*64;

  // Q/K: 8 bf16 per lane, coalesced; rows >= Lb zero
  for (int idx = tid; idx < 640; idx += 320) {    // 80 rows x 8 groups
    int l = idx >> 3, d8 = (idx & 7) * 8;
    uint4 qv = {0,0,0,0}, kv = {0,0,0,0};
    if (l < Lb) {
      const unsigned short* gp = qkv + base + (size_t)l*1536 + d8;
      qv = *(const uint4*)gp;
      kv = *(const uint4*)(gp + 512);
    }
    *(uint4*)(q_s + l*QS + d8) = qv;
    *(uint4*)(k_s + l*QS + d8) = kv;
  }
  // V: coalesced uint4 read (row l, 8 d-elems), swizzled transpose scatter to LDS.
  // vt_s[d][l] stored at d*VS + ((l>>3 ^ (d>>3)&3)<<3) + (l&7); <=2-way banks.
  for (int idx = tid; idx < 768; idx += 320) {    // 96 rows x 8 d-groups
    int l = idx >> 3, d8 = (idx & 7) * 8;
    uint4 vv = {0,0,0,0};
    if (l < Lb) vv = *(const uint4*)(qkv + base + (size_t)l*1536 + 1024 + d8);
    const unsigned short* pv = (const unsigned short*)&vv;
    const int cu = (((l >> 3) ^ ((d8 >> 3) & 3)) << 3) + (l & 7);
    #pragma unroll
    for (int i = 0; i < 8; ++i)
      vt_s[(d8 + i)*VS + cu] = pv[i];
  }
  {
    uint4 z = {0,0,0,0};
    for (int idx = tid; idx < 80*12; idx += 320) {
      int r = idx / 12, cblk = idx % 12;
      *(uint4*)(p_s + r*VS + cblk*8) = z;
    }
  }
  __syncthreads();

  const int s = tid >> 6;                   // one strip per wave, 0..4
  if (s*16 < Lb) {
    const int m0 = s*16;
    bf16x8 aq0 = *(const bf16x8*)(q_s + (m0 + c)*QS + g*8);
    bf16x8 aq1 = *(const bf16x8*)(q_s + (m0 + c)*QS + 32 + g*8);
    f32x4 sc[5];
    #pragma unroll
    for (int nt = 0; nt < 5; ++nt) {
      if (nt < nts) {                       // wave-uniform; static sc index
        bf16x8 bk0 = *(const bf16x8*)(k_s + (nt*16 + c)*QS + g*8);
        bf16x8 bk1 = *(const bf16x8*)(k_s + (nt*16 + c)*QS + 32 + g*8);
        f32x4 z = {};
        z = __builtin_amdgcn_mfma_f32_16x16x32_bf16(aq0, bk0, z, 0, 0, 0);
        sc[nt] = __builtin_amdgcn_mfma_f32_16x16x32_bf16(aq1, bk1, z, 0, 0, 0);
      } else {
        sc[nt] = f32x4{0.f, 0.f, 0.f, 0.f};
      }
    }
    #pragma unroll
    for (int j = 0; j < 4; ++j) {
      int r = m0 + g*4 + j;
      float sv[5];
      float mx = -3.4e38f;
      #pragma unroll
      for (int nt = 0; nt < 5; ++nt) {
        sv[nt] = (nt < nts) ? (sc[nt][j]*0.125f + maskv(r, nt*16 + c, Lb)) : -3.4e38f;
        mx = fmaxf(mx, sv[nt]);
      }
      mx = fmaxf(mx, __shfl_xor(mx, 1));
      mx = fmaxf(mx, __shfl_xor(mx, 2));
      mx = fmaxf(mx, __shfl_xor(mx, 4));
      mx = fmaxf(mx, __shfl_xor(mx, 8));
      float sum = 0.f;
      #pragma unroll
      for (int nt = 0; nt < 5; ++nt) { sv[nt] = __expf(sv[nt] - mx); sum += sv[nt]; }
      sum += __shfl_xor(sum, 1); sum += __shfl_xor(sum, 2);
      sum += __shfl_xor(sum, 4); sum += __shfl_xor(sum, 8);
      float inv = 1.f / sum;
      #pragma unroll
      for (int nt = 0; nt < 5; ++nt)
        if (nt < nts) p_s[r*VS + nt*16 + c] = f2bf(sv[nt] * inv);
    }
    f32x4 oa[4] = {};
    #pragma unroll
    for (int kk = 0; kk < 3; ++kk) {
      if (kk*32 < Lb) {                     // dead 32-col blocks: p and V are zero
        bf16x8 ap = *(const bf16x8*)(p_s + (m0 + c)*VS + kk*32 + g*8);
        #pragma unroll
        for (int nt = 0; nt < 4; ++nt) {
          const int dd = nt*16 + c;
          const int vu = (((kk*4 + g) ^ ((dd >> 3) & 3)) << 3);   // swizzled l-unit
          bf16x8 bv = *(const bf16x8*)(vt_s + dd*VS + vu);
          oa[nt] = __builtin_amdgcn_mfma_f32_16x16x32_bf16(ap, bv, oa[nt], 0, 0, 0);
        }
      }
    }
    #pragma unroll
    for (int nt = 0; nt < 4; ++nt) {
      #pragma unroll
      for (int j = 0; j < 4; ++j) {
        int r = m0 + g*4 + j;
        if (r < Lb)
          O[((size_t)(pb + r))*512 + h*64 + nt*16 + c] = f2bf(oa[nt][j]);
      }
    }
  }
}

extern "C" void kernel_launch(void* const* d_in, const int* in_sizes, int n_in,
                              void* d_out, int out_size, void* d_ws, size_t ws_size,
                              hipStream_t stream) {
  const float* prompts = (const float*)d_in[0];
  const float* pos_emb = (const float*)d_in[1];
  const int*   tokens  = (const int*)d_in[2];
  const float* ln1w    = (const float*)d_in[3];
  const float* ln1b    = (const float*)d_in[4];
  const float* inw     = (const float*)d_in[5];
  const float* inb     = (const float*)d_in[6];
  const float* opw     = (const float*)d_in[7];
  const float* opb     = (const float*)d_in[8];
  const float* ln2w    = (const float*)d_in[9];
  const float* ln2b    = (const float*)d_in[10];
  const float* fcw     = (const float*)d_in[11];
  const float* fcb     = (const float*)d_in[12];
  const float* cpw     = (const float*)d_in[13];
  const float* cpb     = (const float*)d_in[14];
  const float* lnfw    = (const float*)d_in[15];
  const float* lnfb    = (const float*)d_in[16];
  const float* tp      = (const float*)d_in[17];
  float* out = (float*)d_out;

  char* basep = (char*)d_ws;
  size_t off = 0;
  auto carve = [&](size_t bytes) {
    char* p = basep + off;
    off += (bytes + 255) & ~(size_t)255;
    return (void*)p;
  };
  unsigned short* x   = (unsigned short*)carve((size_t)NTOK*DD*2);   // 40.4 MB (bf16 residual)
  unsigned short* hb  = (unsigned short*)carve((size_t)NTOK*DD*2);   // 40.4 MB
  unsigned short* w_tp = (unsigned short*)carve((size_t)512*512*2);
  unsigned short* xe   = (unsigned short*)carve((size_t)BB*DD*2);
  int* len             = (int*)carve((size_t)BB*4);
  int* pref            = (int*)carve((size_t)(BB+1)*4);
  int* mc              = (int*)carve((size_t)4);

  // ---- compaction requires nch=1 (big = full compact qkv/h2 buffer) ----
  const size_t per_layer_w = (size_t)(1536*512 + 512*512 + 2048*512 + 512*2048);
  size_t rem = (ws_size > off) ? (ws_size - off) : 0;
  const size_t big_b = (size_t)NTOK*2048*2 + 1024;
  const size_t wfull = per_layer_w * NLAYER * 2 + 2048;
  const size_t wrot  = per_layer_w * 2 + 2048;
  bool fullw;
  if      (rem >= big_b + wfull) { fullw = true; }
  else if (rem >= big_b + wrot)  { fullw = false; }
  else {
    diag_kernel<<<1, 1, 0, stream>>>(out, 1000.0f + (float)(ws_size >> 20));
    return;
  }

  unsigned short* big = (unsigned short*)carve((size_t)NTOK*2048*2);
  unsigned short *w_in, *w_op, *w_fc, *w_cp;
  size_t stride_in = (size_t)1536*512, stride_op = (size_t)512*512;
  size_t stride_fc = (size_t)2048*512, stride_cp = (size_t)512*2048;
  if (fullw) {
    w_in = (unsigned short*)carve(NLAYER*stride_in*2);
    w_op = (unsigned short*)carve(NLAYER*stride_op*2);
    w_fc = (unsigned short*)carve(NLAYER*stride_fc*2);
    w_cp = (unsigned short*)carve(NLAYER*stride_cp*2);
  } else {
    w_in = (unsigned short*)carve(stride_in*2);
    w_op = (unsigned short*)carve(stride_op*2);
    w_fc = (unsigned short*)carve(stride_fc*2);
    w_cp = (unsigned short*)carve(stride_cp*2);
    stride_in = stride_op = stride_fc = stride_cp = 0;
  }

  lengths_kernel<<<BB, 64, 0, stream>>>(tokens, len);
  scan_kernel<<<1, 512, 0, stream>>>(len, pref, mc);
  embed_kernel<<<NTOK, 128, 0, stream>>>((const float4*)prompts, (const float4*)pos_emb,
                                         len, pref, (uint2*)x);
  tpT_kernel<<<512, 256, 0, stream>>>(tp, w_tp);

  if (fullw) {
    cvt_kernel<<<4096, 256, 0, stream>>>((const float4*)inw, (uint2*)w_in, NLAYER*1536*512/4);
    cvt_kernel<<<4096, 256, 0, stream>>>((const float4*)opw, (uint2*)w_op, NLAYER*512*512/4);
    cvt_kernel<<<4096, 256, 0, stream>>>((const float4*)fcw, (uint2*)w_fc, NLAYER*2048*512/4);
    cvt_kernel<<<4096, 256, 0, stream>>>((const float4*)cpw, (uint2*)w_cp, NLAYER*512*2048/4);
  }

  for (int l = 0; l < NLAYER; ++l) {
    if (!fullw) {
      cvt_kernel<<<512, 256, 0, stream>>>((const float4*)(inw + (size_t)l*1536*512), (uint2*)w_in, 1536*512/4);
      cvt_kernel<<<512, 256, 0, stream>>>((const float4*)(opw + (size_t)l*512*512), (uint2*)w_op, 512*512/4);
      cvt_kernel<<<512, 256, 0, stream>>>((const float4*)(fcw + (size_t)l*2048*512), (uint2*)w_fc, 2048*512/4);
      cvt_kernel<<<512, 256, 0, stream>>>((const float4*)(cpw + (size_t)l*512*2048), (uint2*)w_cp, 512*2048/4);
    }
    const unsigned short* lw_in = w_in + (size_t)l*stride_in;
    const unsigned short* lw_op = w_op + (size_t)l*stride_op;
    const unsigned short* lw_fc = w_fc + (size_t)l*stride_fc;
    const unsigned short* lw_cp = w_cp + (size_t)l*stride_cp;

    ln_kernel<<<NTOK/4, 256, 0, stream>>>(x, ln1w + l*DD, ln1b + l*DD, hb, mc);
    gemm_bt<0><<<dim3(1536/128, NTOK/128), 256, 0, stream>>>(
        hb, lw_in, inb + l*1536, big, nullptr, 1536, 512, mc);
    attn_mfma<<<BB*HH, 320, 0, stream>>>(big, len, pref, hb);
    gemm_bt<2><<<dim3(512/128, NTOK/128), 256, 0, stream>>>(
        hb, lw_op, opb + l*DD, x, nullptr, 512, 512, mc);

    ln_kernel<<<NTOK/4, 256, 0, stream>>>(x, ln2w + l*DD, ln2b + l*DD, hb, mc);
    gemm_bt<1><<<dim3(2048/128, NTOK/128), 256, 0, stream>>>(
        hb, lw_fc, fcb + l*2048, big, nullptr, 2048, 512, mc);
    gemm_bt<2><<<dim3(512/128, NTOK/128), 256, 0, stream>>>(
        big, lw_cp, cpb + l*DD, x, nullptr, 512, 2048, mc);
  }

  eot_ln_kernel<<<BB, 64, 0, stream>>>(x, len, pref, lnfw, lnfb, xe);
  gemm_bt<3><<<dim3(512/128, 512/128), 256, 0, stream>>>(
      xe, w_tp, nullptr, nullptr, out, 512, 512, nullptr);
}

// Round 20
// 3158.859 us; speedup vs baseline: 1.6722x; 1.0910x over previous
//
#include <hip/hip_runtime.h>
#include <hip/hip_bf16.h>
#include <stdint.h>

#define BB 512
#define LL 77
#define DD 512
#define HH 8
#define NLAYER 12
#define NTOK (BB*LL)        // 39424 = 308*128

typedef __bf16 bf16x8 __attribute__((ext_vector_type(8)));
typedef float f32x4 __attribute__((ext_vector_type(4)));

__device__ inline unsigned short f2bf(float f) {
  unsigned u = __float_as_uint(f);
  u += 0x7fffu + ((u >> 16) & 1u);
  return (unsigned short)(u >> 16);
}
__device__ inline float bf2f(unsigned short s) {
  return __uint_as_float(((unsigned)s) << 16);
}
__device__ inline unsigned pack2(float a, float b) {
  return (unsigned)f2bf(a) | ((unsigned)f2bf(b) << 16);
}
__device__ inline void gload16(const void* g, void* l) {
  __builtin_amdgcn_global_load_lds(
      (const __attribute__((address_space(1))) void*)g,
      (__attribute__((address_space(3))) void*)l, 16, 0, 0);
}

__global__ void diag_kernel(float* out, float v) { out[0] = v; }

// ---------------- lengths = argmax(tokens)+1 ----------------
__global__ void lengths_kernel(const int* __restrict__ tok, int* __restrict__ len) {
  int b = blockIdx.x; int lane = threadIdx.x;
  int bv = -2147483647, bi = 0;
  for (int j = lane; j < LL; j += 64) {
    int v = tok[b*LL + j];
    if (v > bv) { bv = v; bi = j; }
  }
  for (int off = 32; off; off >>= 1) {
    int ov = __shfl_down(bv, off);
    int oi = __shfl_down(bi, off);
    if (ov > bv || (ov == bv && oi < bi)) { bv = ov; bi = oi; }
  }
  if (lane == 0) len[b] = bi + 1;
}

// ---------------- exclusive prefix over lengths + total Mc ----------------
__global__ void scan_kernel(const int* __restrict__ len, int* __restrict__ pref,
                            int* __restrict__ mc) {
  __shared__ int sm[512];
  int t = threadIdx.x;
  sm[t] = len[t];
  __syncthreads();
  for (int off = 1; off < 512; off <<= 1) {
    int v = (t >= off) ? sm[t - off] : 0;
    __syncthreads();
    sm[t] += v;
    __syncthreads();
  }
  pref[t + 1] = sm[t];
  if (t == 0) pref[0] = 0;
  if (t == 511) *mc = sm[511];
}

// ---------------- embed (compact gather): x[pref[b]+l] = bf16(prompts+pe) ----------------
__global__ void embed_kernel(const float4* __restrict__ p,
                             const float4* __restrict__ pe,
                             const int* __restrict__ len,
                             const int* __restrict__ pref,
                             uint2* __restrict__ x) {
  int r = blockIdx.x;
  int t = threadIdx.x;           // 0..127, 4 elems each
  int b = r / LL, l = r - b*LL;
  if (l >= len[b]) return;       // dead row
  float4 a = p[(size_t)r*128 + t];
  float4 bb = pe[(size_t)l*128 + t];
  uint2 o; o.x = pack2(a.x+bb.x, a.y+bb.y); o.y = pack2(a.z+bb.z, a.w+bb.w);
  x[(size_t)(pref[b] + l)*128 + t] = o;
}

// mask value per reference where-chain (P=1, C=10 -> [1,11))
__device__ inline float maskv(int i, int j, int Lb) {
  const float NEG = -1e30f;
  float m = (j > i) ? NEG : 0.f;
  bool ctx = (i >= 1 && i < 11);
  if (ctx && j < Lb) m = 0.f;
  if (i >= 11 && i < Lb && j >= 1 && j < 11) m = NEG;
  if (ctx && j >= 1 && j < 11) m = NEG;
  if (j >= Lb) m = NEG;
  bool eot = (i == Lb - 1);
  if (eot && j < 11) m = 0.f;
  if (eot && j >= 11 && j < Lb) m = 0.1f;
  return m;
}

// ---------------- f32 -> bf16 convert ----------------
__global__ void cvt_kernel(const float4* __restrict__ s, uint2* __restrict__ d, int n4) {
  for (int i = blockIdx.x*blockDim.x + threadIdx.x; i < n4; i += gridDim.x*blockDim.x) {
    float4 v = s[i];
    uint2 o; o.x = pack2(v.x, v.y); o.y = pack2(v.z, v.w);
    d[i] = o;
  }
}

// ---------------- transpose text_projection (D,PROJ) -> W[PROJ][D] bf16 ----------------
__global__ void tpT_kernel(const float* __restrict__ tp, unsigned short* __restrict__ W) {
  int p = blockIdx.x;
  for (int d = threadIdx.x; d < DD; d += 256)
    W[(size_t)p*DD + d] = f2bf(tp[(size_t)d*DD + p]);
}

// ---------------- LayerNorm row of 512 (bf16 in) -> bf16 out; compact rows < Mc --------
__global__ __launch_bounds__(256) void ln_kernel(const unsigned short* __restrict__ X,
    const float* __restrict__ w, const float* __restrict__ bia,
    unsigned short* __restrict__ Oh, const int* __restrict__ mcp) {
  int row = blockIdx.x*4 + (threadIdx.x >> 6);
  if (row >= *mcp) return;
  int lane = threadIdx.x & 63;
  uint4 pk = *(const uint4*)(X + (size_t)row*DD + lane*8);
  float v[8];
  v[0]=bf2f(pk.x&0xffff); v[1]=bf2f(pk.x>>16);
  v[2]=bf2f(pk.y&0xffff); v[3]=bf2f(pk.y>>16);
  v[4]=bf2f(pk.z&0xffff); v[5]=bf2f(pk.z>>16);
  v[6]=bf2f(pk.w&0xffff); v[7]=bf2f(pk.w>>16);
  float s = 0.f, q = 0.f;
  #pragma unroll
  for (int i = 0; i < 8; ++i) { s += v[i]; q += v[i]*v[i]; }
  for (int off = 1; off < 64; off <<= 1) { s += __shfl_xor(s, off); q += __shfl_xor(q, off); }
  float mu = s * (1.f/DD);
  float var = q * (1.f/DD) - mu*mu;
  float rs = rsqrtf(var + 1e-5f);
  const float* wp = w + lane*8; const float* bp = bia + lane*8;
  float4 w0 = *(const float4*)wp;  float4 w1 = *(const float4*)(wp+4);
  float4 b0 = *(const float4*)bp;  float4 b1 = *(const float4*)(bp+4);
  float o0 = (v[0]-mu)*rs*w0.x + b0.x;
  float o1 = (v[1]-mu)*rs*w0.y + b0.y;
  float o2 = (v[2]-mu)*rs*w0.z + b0.z;
  float o3 = (v[3]-mu)*rs*w0.w + b0.w;
  float o4 = (v[4]-mu)*rs*w1.x + b1.x;
  float o5 = (v[5]-mu)*rs*w1.y + b1.y;
  float o6 = (v[6]-mu)*rs*w1.z + b1.z;
  float o7 = (v[7]-mu)*rs*w1.w + b1.w;
  uint4 ok; ok.x = pack2(o0,o1); ok.y = pack2(o2,o3); ok.z = pack2(o4,o5); ok.w = pack2(o6,o7);
  *(uint4*)(Oh + (size_t)row*DD + lane*8) = ok;
}

// ---------------- final LN at eot row per batch (compact) ----------------
__global__ void eot_ln_kernel(const unsigned short* __restrict__ X, const int* __restrict__ len,
    const int* __restrict__ pref,
    const float* __restrict__ w, const float* __restrict__ bia,
    unsigned short* __restrict__ Xe) {
  int b = blockIdx.x; int lane = threadIdx.x;
  int row = pref[b] + len[b] - 1;
  uint4 pk = *(const uint4*)(X + (size_t)row*DD + lane*8);
  float v[8];
  v[0]=bf2f(pk.x&0xffff); v[1]=bf2f(pk.x>>16);
  v[2]=bf2f(pk.y&0xffff); v[3]=bf2f(pk.y>>16);
  v[4]=bf2f(pk.z&0xffff); v[5]=bf2f(pk.z>>16);
  v[6]=bf2f(pk.w&0xffff); v[7]=bf2f(pk.w>>16);
  float s = 0.f, q = 0.f;
  #pragma unroll
  for (int i = 0; i < 8; ++i) { s += v[i]; q += v[i]*v[i]; }
  for (int off = 1; off < 64; off <<= 1) { s += __shfl_xor(s, off); q += __shfl_xor(q, off); }
  float mu = s * (1.f/DD);
  float var = q * (1.f/DD) - mu*mu;
  float rs = rsqrtf(var + 1e-5f);
  const float* wp = w + lane*8; const float* bp = bia + lane*8;
  float4 w0 = *(const float4*)wp;  float4 w1 = *(const float4*)(wp+4);
  float4 b0 = *(const float4*)bp;  float4 b1 = *(const float4*)(bp+4);
  float o0 = (v[0]-mu)*rs*w0.x + b0.x;
  float o1 = (v[1]-mu)*rs*w0.y + b0.y;
  float o2 = (v[2]-mu)*rs*w0.z + b0.z;
  float o3 = (v[3]-mu)*rs*w0.w + b0.w;
  float o4 = (v[4]-mu)*rs*w1.x + b1.x;
  float o5 = (v[5]-mu)*rs*w1.y + b1.y;
  float o6 = (v[6]-mu)*rs*w1.z + b1.z;
  float o7 = (v[7]-mu)*rs*w1.w + b1.w;
  uint4 ok; ok.x = pack2(o0,o1); ok.y = pack2(o2,o3); ok.z = pack2(o4,o5); ok.w = pack2(o6,o7);
  *(uint4*)(Xe + (size_t)b*DD + lane*8) = ok;
}

// ---------------- GEMM: C[M,N] = A[M,K] @ W[N,K]^T, BK=64, 32KB LDS, 4 blocks/CU ----------------
// R20: XCD-coherent 1-D swizzle (nbx>0): flat -> xcd=flat&7, i=flat>>3, bx=i%nbx,
// by=(i/nbx)*8+xcd. All blocks sharing an A-panel (same by) get the SAME flat%8 ->
// same XCD (A fetched once, W L2-resident per XCD); dead tail by-rows spread evenly
// over residues (keeps R18's balance). Grid = nbx * pad8(nby); padded rows early-exit.
// nbx==0: plain 2-D blockIdx (final projection).
// EPI 0: bias->bf16. EPI 1: bias+gelu->bf16. EPI 2: residual RMW (LDS slab, uint4). EPI 3: f32.
template<int EPI>
__global__ __launch_bounds__(256, 4) void gemm_bt(
    const unsigned short* __restrict__ A,
    const unsigned short* __restrict__ W,
    const float* __restrict__ bias,
    unsigned short* __restrict__ Ob,
    float* __restrict__ Of,
    int N, int K, const int* __restrict__ mcp, int nbx)
{
  __shared__ __align__(16) char smem[32768];      // As 16KB | Bs 16KB; epilogue slab aliases
  unsigned short* As = (unsigned short*)smem;
  unsigned short* Bs = (unsigned short*)(smem + 16384);
  int bx, by;
  if (nbx > 0) {
    const int flat = blockIdx.x;
    const int xcd = flat & 7, i = flat >> 3;
    bx = i % nbx;
    by = (i / nbx) * 8 + xcd;
  } else {
    bx = blockIdx.x; by = blockIdx.y;
  }
  const int m0 = by * 128, n0 = bx * 128;
  if (mcp && m0 >= *mcp) return;                  // dead token tile (incl. pad rows)
  const int tid = threadIdx.x;
  const int lane = tid & 63;
  const int wid = tid >> 6;
  const int wr = wid >> 1, wc = wid & 1;

  f32x4 acc[4][4] = {};

  const int r0 = tid >> 3;                       // 0..31 (row within 32-row group)
  const int cb = (((tid & 7) ^ (r0 & 7)) * 8);   // swizzled source 16B-unit
  const unsigned voff = (unsigned)(r0 * K + cb); // per-thread, loop-invariant

  const int c = lane & 15, gq = lane >> 4;
  const int aBase = (wr*64 + c)*64;
  const int bBase = (wc*64 + c)*64;
  const int sw0 = ((0*4 + gq) ^ (c & 7)) * 8;
  const int sw1 = ((1*4 + gq) ^ (c & 7)) * 8;

  for (int k0 = 0; k0 < K; k0 += 64) {
    const unsigned short* pA = A + (size_t)m0 * K + k0;   // wave-uniform (SGPR)
    const unsigned short* pW = W + (size_t)n0 * K + k0;
    #pragma unroll
    for (int g = 0; g < 4; ++g) {
      gload16(pA + (size_t)g*32*K + voff, As + g*2048 + tid*8);
      gload16(pW + (size_t)g*32*K + voff, Bs + g*2048 + tid*8);
    }
    __syncthreads();
    #pragma unroll
    for (int kk = 0; kk < 2; ++kk) {
      const int sw = kk ? sw1 : sw0;
      bf16x8 af[4], bfr[4];
      #pragma unroll
      for (int mi = 0; mi < 4; ++mi)
        af[mi] = *(const bf16x8*)(As + aBase + sw + mi*1024);
      #pragma unroll
      for (int ni = 0; ni < 4; ++ni)
        bfr[ni] = *(const bf16x8*)(Bs + bBase + sw + ni*1024);
      #pragma unroll
      for (int mi = 0; mi < 4; ++mi)
        #pragma unroll
        for (int ni = 0; ni < 4; ++ni)
          acc[mi][ni] = __builtin_amdgcn_mfma_f32_16x16x32_bf16(af[mi], bfr[ni], acc[mi][ni], 0, 0, 0);
    }
    __syncthreads();
  }

  if constexpr (EPI == 2) {
    // per-wave private f32 slab [16][68] (pad 68 -> 2-way-free writes), 4352 B/wave
    float* slab = (float*)smem + wid*1088;
    const int rr = lane >> 3;            // 0..7
    const int c8 = (lane & 7) * 8;       // 0..56
    const int gcol = n0 + wc*64 + c8;
    float4 bq0 = *(const float4*)(bias + gcol);
    float4 bq1 = *(const float4*)(bias + gcol + 4);
    float badd[8] = {bq0.x,bq0.y,bq0.z,bq0.w,bq1.x,bq1.y,bq1.z,bq1.w};
    #pragma unroll
    for (int mi = 0; mi < 4; ++mi) {
      #pragma unroll
      for (int ni = 0; ni < 4; ++ni)
        #pragma unroll
        for (int j = 0; j < 4; ++j)
          slab[(gq*4 + j)*68 + ni*16 + c] = acc[mi][ni][j];
      #pragma unroll
      for (int q = 0; q < 2; ++q) {
        int r = q*8 + rr;
        int grow = m0 + wr*64 + mi*16 + r;
        size_t ix = (size_t)grow * N + gcol;
        uint4 old = *(const uint4*)(Ob + ix);
        float vv[8];
        #pragma unroll
        for (int i = 0; i < 8; ++i) vv[i] = slab[r*68 + c8 + i] + badd[i];
        unsigned ow[4] = {old.x, old.y, old.z, old.w};
        uint4 res; unsigned* rp = (unsigned*)&res;
        #pragma unroll
        for (int h = 0; h < 4; ++h) {
          float a0 = vv[h*2]   + bf2f((unsigned short)(ow[h] & 0xffff));
          float a1 = vv[h*2+1] + bf2f((unsigned short)(ow[h] >> 16));
          rp[h] = pack2(a0, a1);
        }
        *(uint4*)(Ob + ix) = res;      // 16B/lane coalesced full-line RMW
      }
    }
  } else {
    const int rbase = m0 + wr*64 + gq*4;
    const int cbase = n0 + wc*64 + c;
    #pragma unroll
    for (int mi = 0; mi < 4; ++mi) {
      #pragma unroll
      for (int ni = 0; ni < 4; ++ni) {
        int col = cbase + ni*16;
        float bv = 0.f;
        if constexpr (EPI != 3) bv = bias[col];
        #pragma unroll
        for (int j = 0; j < 4; ++j) {
          int row = rbase + mi*16 + j;
          float v = acc[mi][ni][j] + bv;
          size_t ix = (size_t)row*N + col;
          if constexpr (EPI == 0) {
            Ob[ix] = f2bf(v);
          } else if constexpr (EPI == 1) {
            float sg = 1.f/(1.f + __expf(-1.702f*v));
            Ob[ix] = f2bf(v*sg);
          } else {
            Of[ix] = v;
          }
        }
      }
    }
  }
}

// ---------------- MFMA attention: one block per (b,h), 5 waves, compact rows --------
#define QS 72    // q/k LDS row stride (elems); +8 pad -> conflict-free frag reads
#define VS 104   // vt/p LDS row stride (elems); 13 units of 8 (swizzle uses units 0..11^0..3)

__global__ __launch_bounds__(320) void attn_mfma(
    const unsigned short* __restrict__ qkv,   // [Mc][1536] compact bf16
    const int* __restrict__ len,
    const int* __restrict__ pref,
    unsigned short* __restrict__ O)           // [Mc][512] compact bf16
{
  __shared__ __align__(16) unsigned short q_s[80*QS];
  __shared__ __align__(16) unsigned short k_s[80*QS];
  __shared__ __align__(16) unsigned short vt_s[64*VS];
  __shared__ __align__(16) unsigned short p_s[80*VS];
  const int bh = blockIdx.x;
  const int b = bh >> 3, h = bh & 7;
  const int tid = threadIdx.x, lane = tid & 63, g = lane >> 4, c = lane & 15;
  const int Lb = len[b];
  const int pb = pref[b];
  const int nts = (Lb + 15) >> 4;           // live 16-col K-tiles (1..5)
  const size_t base = (size_t)pb*1536 + h*64;

  for (int idx = tid; idx < 640; idx += 320) {    // 80 rows x 8 groups
    int l = idx >> 3, d8 = (idx & 7) * 8;
    uint4 qv = {0,0,0,0}, kv = {0,0,0,0};
    if (l < Lb) {
      const unsigned short* gp = qkv + base + (size_t)l*1536 + d8;
      qv = *(const uint4*)gp;
      kv = *(const uint4*)(gp + 512);
    }
    *(uint4*)(q_s + l*QS + d8) = qv;
    *(uint4*)(k_s + l*QS + d8) = kv;
  }
  // V: coalesced uint4 read, swizzled transpose scatter (unit ^= (d>>3)&3, <=2-way)
  for (int idx = tid; idx < 768; idx += 320) {    // 96 rows x 8 d-groups
    int l = idx >> 3, d8 = (idx & 7) * 8;
    uint4 vv = {0,0,0,0};
    if (l < Lb) vv = *(const uint4*)(qkv + base + (size_t)l*1536 + 1024 + d8);
    const unsigned short* pv = (const unsigned short*)&vv;
    const int cu = (((l >> 3) ^ ((d8 >> 3) & 3)) << 3) + (l & 7);
    #pragma unroll
    for (int i = 0; i < 8; ++i)
      vt_s[(d8 + i)*VS + cu] = pv[i];
  }
  {
    uint4 z = {0,0,0,0};
    for (int idx = tid; idx < 80*12; idx += 320) {
      int r = idx / 12, cblk = idx % 12;
      *(uint4*)(p_s + r*VS + cblk*8) = z;
    }
  }
  __syncthreads();

  const int s = tid >> 6;                   // one strip per wave, 0..4
  if (s*16 < Lb) {
    const int m0 = s*16;
    bf16x8 aq0 = *(const bf16x8*)(q_s + (m0 + c)*QS + g*8);
    bf16x8 aq1 = *(const bf16x8*)(q_s + (m0 + c)*QS + 32 + g*8);
    f32x4 sc[5];
    #pragma unroll
    for (int nt = 0; nt < 5; ++nt) {
      if (nt < nts) {                       // wave-uniform; static sc index
        bf16x8 bk0 = *(const bf16x8*)(k_s + (nt*16 + c)*QS + g*8);
        bf16x8 bk1 = *(const bf16x8*)(k_s + (nt*16 + c)*QS + 32 + g*8);
        f32x4 z = {};
        z = __builtin_amdgcn_mfma_f32_16x16x32_bf16(aq0, bk0, z, 0, 0, 0);
        sc[nt] = __builtin_amdgcn_mfma_f32_16x16x32_bf16(aq1, bk1, z, 0, 0, 0);
      } else {
        sc[nt] = f32x4{0.f, 0.f, 0.f, 0.f};
      }
    }
    #pragma unroll
    for (int j = 0; j < 4; ++j) {
      int r = m0 + g*4 + j;
      float sv[5];
      float mx = -3.4e38f;
      #pragma unroll
      for (int nt = 0; nt < 5; ++nt) {
        sv[nt] = (nt < nts) ? (sc[nt][j]*0.125f + maskv(r, nt*16 + c, Lb)) : -3.4e38f;
        mx = fmaxf(mx, sv[nt]);
      }
      mx = fmaxf(mx, __shfl_xor(mx, 1));
      mx = fmaxf(mx, __shfl_xor(mx, 2));
      mx = fmaxf(mx, __shfl_xor(mx, 4));
      mx = fmaxf(mx, __shfl_xor(mx, 8));
      float sum = 0.f;
      #pragma unroll
      for (int nt = 0; nt < 5; ++nt) { sv[nt] = __expf(sv[nt] - mx); sum += sv[nt]; }
      sum += __shfl_xor(sum, 1); sum += __shfl_xor(sum, 2);
      sum += __shfl_xor(sum, 4); sum += __shfl_xor(sum, 8);
      float inv = 1.f / sum;
      #pragma unroll
      for (int nt = 0; nt < 5; ++nt)
        if (nt < nts) p_s[r*VS + nt*16 + c] = f2bf(sv[nt] * inv);
    }
    f32x4 oa[4] = {};
    #pragma unroll
    for (int kk = 0; kk < 3; ++kk) {
      if (kk*32 < Lb) {                     // dead 32-col blocks: p and V are zero
        bf16x8 ap = *(const bf16x8*)(p_s + (m0 + c)*VS + kk*32 + g*8);
        #pragma unroll
        for (int nt = 0; nt < 4; ++nt) {
          const int dd = nt*16 + c;
          const int vu = (((kk*4 + g) ^ ((dd >> 3) & 3)) << 3);   // swizzled l-unit
          bf16x8 bv = *(const bf16x8*)(vt_s + dd*VS + vu);
          oa[nt] = __builtin_amdgcn_mfma_f32_16x16x32_bf16(ap, bv, oa[nt], 0, 0, 0);
        }
      }
    }
    #pragma unroll
    for (int nt = 0; nt < 4; ++nt) {
      #pragma unroll
      for (int j = 0; j < 4; ++j) {
        int r = m0 + g*4 + j;
        if (r < Lb)
          O[((size_t)(pb + r))*512 + h*64 + nt*16 + c] = f2bf(oa[nt][j]);
      }
    }
  }
}

extern "C" void kernel_launch(void* const* d_in, const int* in_sizes, int n_in,
                              void* d_out, int out_size, void* d_ws, size_t ws_size,
                              hipStream_t stream) {
  const float* prompts = (const float*)d_in[0];
  const float* pos_emb = (const float*)d_in[1];
  const int*   tokens  = (const int*)d_in[2];
  const float* ln1w    = (const float*)d_in[3];
  const float* ln1b    = (const float*)d_in[4];
  const float* inw     = (const float*)d_in[5];
  const float* inb     = (const float*)d_in[6];
  const float* opw     = (const float*)d_in[7];
  const float* opb     = (const float*)d_in[8];
  const float* ln2w    = (const float*)d_in[9];
  const float* ln2b    = (const float*)d_in[10];
  const float* fcw     = (const float*)d_in[11];
  const float* fcb     = (const float*)d_in[12];
  const float* cpw     = (const float*)d_in[13];
  const float* cpb     = (const float*)d_in[14];
  const float* lnfw    = (const float*)d_in[15];
  const float* lnfb    = (const float*)d_in[16];
  const float* tp      = (const float*)d_in[17];
  float* out = (float*)d_out;

  char* basep = (char*)d_ws;
  size_t off = 0;
  auto carve = [&](size_t bytes) {
    char* p = basep + off;
    off += (bytes + 255) & ~(size_t)255;
    return (void*)p;
  };
  unsigned short* x   = (unsigned short*)carve((size_t)NTOK*DD*2);   // 40.4 MB (bf16 residual)
  unsigned short* hb  = (unsigned short*)carve((size_t)NTOK*DD*2);   // 40.4 MB
  unsigned short* w_tp = (unsigned short*)carve((size_t)512*512*2);
  unsigned short* xe   = (unsigned short*)carve((size_t)BB*DD*2);
  int* len             = (int*)carve((size_t)BB*4);
  int* pref            = (int*)carve((size_t)(BB+1)*4);
  int* mc              = (int*)carve((size_t)4);

  // ---- compaction requires nch=1 (big = full compact qkv/h2 buffer) ----
  const size_t per_layer_w = (size_t)(1536*512 + 512*512 + 2048*512 + 512*2048);
  size_t rem = (ws_size > off) ? (ws_size - off) : 0;
  const size_t big_b = (size_t)NTOK*2048*2 + 1024;
  const size_t wfull = per_layer_w * NLAYER * 2 + 2048;
  const size_t wrot  = per_layer_w * 2 + 2048;
  bool fullw;
  if      (rem >= big_b + wfull) { fullw = true; }
  else if (rem >= big_b + wrot)  { fullw = false; }
  else {
    diag_kernel<<<1, 1, 0, stream>>>(out, 1000.0f + (float)(ws_size >> 20));
    return;
  }

  unsigned short* big = (unsigned short*)carve((size_t)NTOK*2048*2);
  unsigned short *w_in, *w_op, *w_fc, *w_cp;
  size_t stride_in = (size_t)1536*512, stride_op = (size_t)512*512;
  size_t stride_fc = (size_t)2048*512, stride_cp = (size_t)512*2048;
  if (fullw) {
    w_in = (unsigned short*)carve(NLAYER*stride_in*2);
    w_op = (unsigned short*)carve(NLAYER*stride_op*2);
    w_fc = (unsigned short*)carve(NLAYER*stride_fc*2);
    w_cp = (unsigned short*)carve(NLAYER*stride_cp*2);
  } else {
    w_in = (unsigned short*)carve(stride_in*2);
    w_op = (unsigned short*)carve(stride_op*2);
    w_fc = (unsigned short*)carve(stride_fc*2);
    w_cp = (unsigned short*)carve(stride_cp*2);
    stride_in = stride_op = stride_fc = stride_cp = 0;
  }

  lengths_kernel<<<BB, 64, 0, stream>>>(tokens, len);
  scan_kernel<<<1, 512, 0, stream>>>(len, pref, mc);
  embed_kernel<<<NTOK, 128, 0, stream>>>((const float4*)prompts, (const float4*)pos_emb,
                                         len, pref, (uint2*)x);
  tpT_kernel<<<512, 256, 0, stream>>>(tp, w_tp);

  if (fullw) {
    cvt_kernel<<<4096, 256, 0, stream>>>((const float4*)inw, (uint2*)w_in, NLAYER*1536*512/4);
    cvt_kernel<<<4096, 256, 0, stream>>>((const float4*)opw, (uint2*)w_op, NLAYER*512*512/4);
    cvt_kernel<<<4096, 256, 0, stream>>>((const float4*)fcw, (uint2*)w_fc, NLAYER*2048*512/4);
    cvt_kernel<<<4096, 256, 0, stream>>>((const float4*)cpw, (uint2*)w_cp, NLAYER*512*2048/4);
  }

  const int NBY = 312;              // pad8(308); rows 308..311 always dead (m0 > Mc)
  for (int l = 0; l < NLAYER; ++l) {
    if (!fullw) {
      cvt_kernel<<<512, 256, 0, stream>>>((const float4*)(inw + (size_t)l*1536*512), (uint2*)w_in, 1536*512/4);
      cvt_kernel<<<512, 256, 0, stream>>>((const float4*)(opw + (size_t)l*512*512), (uint2*)w_op, 512*512/4);
      cvt_kernel<<<512, 256, 0, stream>>>((const float4*)(fcw + (size_t)l*2048*512), (uint2*)w_fc, 2048*512/4);
      cvt_kernel<<<512, 256, 0, stream>>>((const float4*)(cpw + (size_t)l*512*2048), (uint2*)w_cp, 512*2048/4);
    }
    const unsigned short* lw_in = w_in + (size_t)l*stride_in;
    const unsigned short* lw_op = w_op + (size_t)l*stride_op;
    const unsigned short* lw_fc = w_fc + (size_t)l*stride_fc;
    const unsigned short* lw_cp = w_cp + (size_t)l*stride_cp;

    ln_kernel<<<NTOK/4, 256, 0, stream>>>(x, ln1w + l*DD, ln1b + l*DD, hb, mc);
    gemm_bt<0><<<12*NBY, 256, 0, stream>>>(
        hb, lw_in, inb + l*1536, big, nullptr, 1536, 512, mc, 12);
    attn_mfma<<<BB*HH, 320, 0, stream>>>(big, len, pref, hb);
    gemm_bt<2><<<4*NBY, 256, 0, stream>>>(
        hb, lw_op, opb + l*DD, x, nullptr, 512, 512, mc, 4);

    ln_kernel<<<NTOK/4, 256, 0, stream>>>(x, ln2w + l*DD, ln2b + l*DD, hb, mc);
    gemm_bt<1><<<16*NBY, 256, 0, stream>>>(
        hb, lw_fc, fcb + l*2048, big, nullptr, 2048, 512, mc, 16);
    gemm_bt<2><<<4*NBY, 256, 0, stream>>>(
        big, lw_cp, cpb + l*DD, x, nullptr, 512, 2048, mc, 4);
  }

  eot_ln_kernel<<<BB, 64, 0, stream>>>(x, len, pref, lnfw, lnfb, xe);
  gemm_bt<3><<<dim3(512/128, 512/128), 256, 0, stream>>>(
      xe, w_tp, nullptr, nullptr, out, 512, 512, nullptr, 0);
}